// Round 11
// baseline (636.216 us; speedup 1.0000x reference)
//
#include <hip/hip_runtime.h>

#define DEVI __device__ __forceinline__

using u16 = unsigned short;
using u32 = unsigned int;

typedef __attribute__((ext_vector_type(8))) short short8v;
typedef __attribute__((ext_vector_type(4))) float f32x4;
typedef __attribute__((ext_vector_type(16))) float f32x16;
typedef __attribute__((ext_vector_type(2))) u32 u32x2;
typedef __attribute__((ext_vector_type(4))) u32 u32x4;

DEVI u16 f2b(float f) {
  u32 u = __builtin_bit_cast(u32, f);
  u += 0x7fffu + ((u >> 16) & 1u);
  return (u16)(u >> 16);
}
DEVI float b2f(u16 b) { return __builtin_bit_cast(float, (u32)b << 16); }

DEVI void gload16(const void* g, void* l) {
  __builtin_amdgcn_global_load_lds(
      (const __attribute__((address_space(1))) void*)g,
      (__attribute__((address_space(3))) void*)l, 16, 0, 0);
}

// ---------------- x: fp32 -> bf16 ----------------
__global__ __launch_bounds__(256) void cvt_x_k(const float* __restrict__ in,
                                               u16* __restrict__ out) {
  size_t i = ((size_t)blockIdx.x * 256 + threadIdx.x) * 8;
  f32x4 a = *(const f32x4*)(in + i);
  f32x4 c = *(const f32x4*)(in + i + 4);
  short8v o;
  o[0] = (short)f2b(a[0]); o[1] = (short)f2b(a[1]);
  o[2] = (short)f2b(a[2]); o[3] = (short)f2b(a[3]);
  o[4] = (short)f2b(c[0]); o[5] = (short)f2b(c[1]);
  o[6] = (short)f2b(c[2]); o[7] = (short)f2b(c[3]);
  *(short8v*)(out + i) = o;
}

// ---------------- transpose + cvt ----------------
__global__ __launch_bounds__(256) void transpose_cvt_k(
    const float* __restrict__ in, u16* __restrict__ out, int R, int Ccols) {
  __shared__ u16 tile[64][65];
  const int r0 = blockIdx.y * 64, c0 = blockIdx.x * 64;
  const int tx = threadIdx.x & 63, ty = threadIdx.x >> 6;
#pragma unroll
  for (int jj = 0; jj < 16; ++jj) {
    int r = ty + jj * 4;
    tile[r][tx] = f2b(in[(size_t)(r0 + r) * Ccols + c0 + tx]);
  }
  __syncthreads();
#pragma unroll
  for (int jj = 0; jj < 16; ++jj) {
    int c = ty + jj * 4;
    out[(size_t)(c0 + c) * R + r0 + tx] = tile[tx][c];
  }
}

// ---------------- rope table ----------------
__global__ __launch_bounds__(256) void rope_table_k(float* __restrict__ cosT,
                                                    float* __restrict__ sinT) {
  int idx = blockIdx.x * 256 + threadIdx.x;
  int s = idx >> 6, i = idx & 63;
  float inv_freq = expf(-(float)i * (1.0f / 64.0f) * 9.210340371976184f);
  float ang = (float)s * inv_freq;
  cosT[idx] = cosf(ang);
  sinT[idx] = sinf(ang);
}

// ---------------- rope + scatter q,k (q pre-scaled by 1/sqrt(hd)*log2e) ----
__global__ __launch_bounds__(256) void rope_scatter_k(
    const u16* __restrict__ qkv, const float* __restrict__ cosT,
    const float* __restrict__ sinT, u16* __restrict__ q_r,
    u16* __restrict__ k_r) {
  const float QS = 0.08838834764831845f * 1.4426950408889634f;
  const int row = blockIdx.x;
  const int b = row >> 11, s = row & 2047;
  const u16* in = qkv + (size_t)row * 3072;
  const float* cp = cosT + s * 64;
  const float* sp = sinT + s * 64;
  for (int p = threadIdx.x; p < 1280; p += 256) {
    int f0 = p * 2;
    u32 pair = *(const u32*)(in + f0);
    float x0 = b2f((u16)(pair & 0xffffu));
    float x1 = b2f((u16)(pair >> 16));
    int d, head;
    u16* dst;
    bool isq = (f0 < 2048);
    if (isq) {
      head = f0 >> 7; d = f0 & 127;
      dst = q_r + (((size_t)(b * 16 + head)) * 2048 + s) * 128 + d;
    } else {
      int idx = f0 - 2048;
      head = idx >> 7; d = idx & 127;
      dst = k_r + (((size_t)(b * 4 + head)) * 2048 + s) * 128 + d;
    }
    int i = d >> 1;
    float c = cp[i], sn = sp[i];
    float o0 = x0 * c - x1 * sn;
    float o1 = x0 * sn + x1 * c;
    if (isq) { o0 *= QS; o1 *= QS; }
    *(u32*)dst = (u32)f2b(o0) | ((u32)f2b(o1) << 16);
  }
}

// ---------------- v transpose ----------------
__global__ __launch_bounds__(256) void v_trans_k(const u16* __restrict__ qkv,
                                                 u16* __restrict__ vT) {
  __shared__ u16 tile[64][65];
  const int s0 = blockIdx.x * 64, d0 = blockIdx.y * 64;
  const int bk = blockIdx.z;
  const int b = bk >> 2, kh = bk & 3;
  const int tx = threadIdx.x & 63, ty = threadIdx.x >> 6;
  const u16* src = qkv + ((size_t)b * 2048) * 3072 + 2560 + kh * 128;
#pragma unroll
  for (int jj = 0; jj < 16; ++jj) {
    int s = ty + jj * 4;
    tile[s][tx] = src[(size_t)(s0 + s) * 3072 + d0 + tx];
  }
  __syncthreads();
  u16* dst = vT + (((size_t)bk * 128 + d0) * 2048) + s0;
#pragma unroll
  for (int jj = 0; jj < 16; ++jj) {
    int dd = ty + jj * 4;
    dst[(size_t)dd * 2048 + tx] = tile[tx][dd];
  }
}

// ---------------- 256x256 8-phase GEMM ----------------
DEVI short8v ldf(const char* half, int r, int slot) {
  return *(const short8v*)(half + r * 64 + (((slot) ^ (r & 3)) << 4));
}

DEVI void stg(const u16* __restrict__ G, int row0, int Kd, int T, int kh,
              char* dst, int t, int w) {
#pragma unroll
  for (int i = 0; i < 2; ++i) {
    int off = i * 8192 + t * 16;
    int r = off >> 6;
    int gs = ((off >> 4) & 3) ^ (r & 3);
    gload16((const char*)G +
                (((size_t)(row0 + r) * Kd) + T * 64 + kh * 32 + gs * 8) * 2,
            dst + i * 8192 + w * 1024);
  }
}

#define VM4 asm volatile("s_waitcnt vmcnt(4)" ::: "memory")
#define PH(P2, KS, CH, STAGE_STMT, TAILWAIT)                                   \
  {                                                                            \
    if ((CH) == 0) {                                                           \
      _Pragma("unroll") for (int mt = 0; mt < 8; ++mt) af[mt] =                \
          ldf(Ab + (P2) * 32768 + (KS) * 16384, wm * 128 + mt * 16 + lo, hi);  \
    }                                                                          \
    bf0 = ldf(Bb + (P2) * 32768 + (KS) * 16384, wn * 64 + (CH) * 32 + lo, hi);\
    bf1 = ldf(Bb + (P2) * 32768 + (KS) * 16384,                                \
              wn * 64 + (CH) * 32 + 16 + lo, hi);                              \
    STAGE_STMT;                                                                \
    __builtin_amdgcn_sched_barrier(0);                                         \
    __builtin_amdgcn_s_barrier();                                              \
    asm volatile("s_waitcnt lgkmcnt(0)" ::: "memory");                         \
    __builtin_amdgcn_sched_barrier(0);                                         \
    __builtin_amdgcn_s_setprio(1);                                             \
    _Pragma("unroll") for (int mt = 0; mt < 8; ++mt) {                         \
      acc[mt][(CH) * 2] = __builtin_amdgcn_mfma_f32_16x16x32_bf16(             \
          af[mt], bf0, acc[mt][(CH) * 2], 0, 0, 0);                            \
      acc[mt][(CH) * 2 + 1] = __builtin_amdgcn_mfma_f32_16x16x32_bf16(         \
          af[mt], bf1, acc[mt][(CH) * 2 + 1], 0, 0, 0);                        \
    }                                                                          \
    __builtin_amdgcn_s_setprio(0);                                             \
    TAILWAIT;                                                                  \
    __builtin_amdgcn_sched_barrier(0);                                         \
    __builtin_amdgcn_s_barrier();                                              \
    __builtin_amdgcn_sched_barrier(0);                                         \
  }

__global__ __launch_bounds__(512, 2) void gemm256_k(const u16* __restrict__ A,
                                                    const u16* __restrict__ BT,
                                                    u16* __restrict__ C, int N,
                                                    int Kd) {
  __shared__ __align__(16) char lds[131072];
  char* Ab = lds;
  char* Bb = lds + 65536;

  const int t = threadIdx.x;
  const int lane = t & 63, lo = lane & 15, hi = lane >> 4;
  const int w = t >> 6, wm = w >> 2, wn = w & 3;

  const int ntx = gridDim.x;
  const int nwg = ntx * gridDim.y;
  const int orig = blockIdx.y * ntx + blockIdx.x;
  const int cpx = nwg >> 3;
  const int swz = (orig & 7) * cpx + (orig >> 3);
  const int m0 = (swz / ntx) * 256, n0 = (swz % ntx) * 256;

  f32x4 acc[8][4];
#pragma unroll
  for (int a = 0; a < 8; ++a)
#pragma unroll
    for (int c = 0; c < 4; ++c) acc[a][c] = (f32x4){0.f, 0.f, 0.f, 0.f};

  short8v af[8], bf0, bf1;

  const int NK = Kd >> 6;
  const int NK2 = NK >> 1;

  stg(A, m0, Kd, 0, 0, Ab + 0, t, w);
  stg(BT, n0, Kd, 0, 0, Bb + 0, t, w);
  stg(A, m0, Kd, 0, 1, Ab + 16384, t, w);
  stg(BT, n0, Kd, 0, 1, Bb + 16384, t, w);
  stg(A, m0, Kd, 1, 0, Ab + 32768, t, w);
  stg(BT, n0, Kd, 1, 0, Bb + 32768, t, w);
  VM4;
  __builtin_amdgcn_sched_barrier(0);
  __builtin_amdgcn_s_barrier();
  __builtin_amdgcn_sched_barrier(0);

  for (int kt2 = 0; kt2 < NK2; ++kt2) {
    int T1v = 2 * kt2 + 1;
    int T2v = 2 * kt2 + 2; if (T2v > NK - 1) T2v = NK - 1;
    int T3v = 2 * kt2 + 3; if (T3v > NK - 1) T3v = NK - 1;
    PH(0, 0, 0, stg(A, m0, Kd, T1v, 1, Ab + 49152, t, w), (void)0);
    PH(0, 0, 1, stg(BT, n0, Kd, T1v, 1, Bb + 49152, t, w), (void)0);
    PH(0, 1, 0, stg(A, m0, Kd, T2v, 0, Ab + 0, t, w), (void)0);
    PH(0, 1, 1, stg(BT, n0, Kd, T2v, 0, Bb + 0, t, w), VM4);
    PH(1, 0, 0, stg(A, m0, Kd, T2v, 1, Ab + 16384, t, w), (void)0);
    PH(1, 0, 1, stg(BT, n0, Kd, T2v, 1, Bb + 16384, t, w), (void)0);
    PH(1, 1, 0, stg(A, m0, Kd, T3v, 0, Ab + 32768, t, w), (void)0);
    PH(1, 1, 1, stg(BT, n0, Kd, T3v, 0, Bb + 32768, t, w), VM4);
  }
  asm volatile("s_waitcnt vmcnt(0)" ::: "memory");

#pragma unroll
  for (int mt = 0; mt < 8; ++mt)
#pragma unroll
    for (int nt = 0; nt < 4; ++nt)
#pragma unroll
      for (int r = 0; r < 4; ++r) {
        int row = m0 + wm * 128 + mt * 16 + hi * 4 + r;
        int col = n0 + wn * 64 + nt * 16 + lo;
        C[(size_t)row * N + col] = f2b(acc[mt][nt][r]);
      }
}

// ---------------- flash attention: cache-direct, zero-LDS, zero-barrier -----
// K/V per (b,kh) = 1MB, L2-resident (2 pairs/XCD via swizzle). Each wave
// reads K/V fragments straight from global (L1/L2 serve re-reads across the
// block's 4 waves). No __shared__, no sync — waves fully independent; the
// compiler pipelines next-tile loads under current-tile softmax freely.
// Swapped 32x32 MFMA, lane-local softmax, in-register P^T (permlane swap).
__global__ __launch_bounds__(256, 2) void attn_k(const u16* __restrict__ Q,
                                                 const u16* __restrict__ K,
                                                 const u16* __restrict__ VT,
                                                 u16* __restrict__ Y) {
  const int t = threadIdx.x;
  const int lane = t & 63;
  const int l31 = lane & 31, hb = lane >> 5;
  const int w = t >> 6;

  // (b,kh)-grouping swizzle: 2 pairs per XCD -> 2MB KV in each XCD's L2.
  const int id = blockIdx.x;          // 1024 blocks
  const int xcd = id & 7, idx = id >> 3;      // idx: 0..127
  const int pair = xcd * 2 + (idx >> 6);      // 0..15 = (b,kh)
  const int b = pair >> 2, kh = pair & 3;
  const int h = kh * 4 + ((idx >> 4) & 3);
  const int qt = 15 - (idx & 15);             // heavy q-tiles first

  const size_t qbase = (size_t)(b * 16 + h) * 2048 * 128;
  const u16* Kp = K + (size_t)(b * 4 + kh) * 2048 * 128;
  const u16* Vp = VT + (size_t)(b * 4 + kh) * 128 * 2048;

  const int q0 = qt * 128;
  const int qrow = q0 + w * 32 + l31;

  // Q fragments: B-operand, q = lane&31, d = j16*16 + hb*8 + e
  short8v qf[8];
#pragma unroll
  for (int j16 = 0; j16 < 8; ++j16)
    qf[j16] = *(const short8v*)(Q + qbase + (size_t)qrow * 128 + j16 * 16 + hb * 8);

  float m_run = -3.0e38f, l_run = 0.f;
  f32x16 oacc[4];
#pragma unroll
  for (int db = 0; db < 4; ++db)
#pragma unroll
    for (int rg = 0; rg < 16; ++rg) oacc[db][rg] = 0.f;

  const int ntile = 2 * qt + 2;

  for (int jj = 0; jj < ntile; ++jj) {
    const int kv0 = jj * 64;

    // QK^T: S^T[k][q], k = kv0 + kb*32 + (rg&3)+8*(rg>>2)+4*hb, q = qrow
    f32x16 sacc[2];
#pragma unroll
    for (int kb = 0; kb < 2; ++kb)
#pragma unroll
      for (int rg = 0; rg < 16; ++rg) sacc[kb][rg] = 0.f;

    __builtin_amdgcn_s_setprio(1);
#pragma unroll
    for (int j16 = 0; j16 < 8; ++j16) {
#pragma unroll
      for (int kb = 0; kb < 2; ++kb) {
        short8v kf = *(const short8v*)(Kp +
            (size_t)(kv0 + kb * 32 + l31) * 128 + j16 * 16 + hb * 8);
        sacc[kb] = __builtin_amdgcn_mfma_f32_32x32x16_bf16(kf, qf[j16],
                                                           sacc[kb], 0, 0, 0);
      }
    }
    __builtin_amdgcn_s_setprio(0);

    // causal mask (last two tiles cover the diagonal 128-block)
    if (jj >= ntile - 2) {
      const int mb = kv0 + 4 * hb - qrow;
#pragma unroll
      for (int kb = 0; kb < 2; ++kb)
#pragma unroll
        for (int rg = 0; rg < 16; ++rg)
          if (mb + kb * 32 + (rg & 3) + 8 * (rg >> 2) > 0)
            sacc[kb][rg] = -1.0e38f;
    }

    // row max: pairwise tree + 1 cross-half shfl
    float mt0[16];
#pragma unroll
    for (int rg = 0; rg < 16; ++rg) mt0[rg] = fmaxf(sacc[0][rg], sacc[1][rg]);
#pragma unroll
    for (int rg = 0; rg < 8; ++rg) mt0[rg] = fmaxf(mt0[rg], mt0[rg + 8]);
#pragma unroll
    for (int rg = 0; rg < 4; ++rg) mt0[rg] = fmaxf(mt0[rg], mt0[rg + 4]);
    float mx = fmaxf(fmaxf(mt0[0], mt0[1]), fmaxf(mt0[2], mt0[3]));
    mx = fmaxf(mx, __shfl_xor(mx, 32, 64));

    // defer-max rescale
    if (__any(mx > m_run + 8.f)) {
      float mn = fmaxf(m_run, mx);
      float corr = exp2f(m_run - mn);
      m_run = mn;
      l_run *= corr;
#pragma unroll
      for (int db = 0; db < 4; ++db)
#pragma unroll
        for (int rg = 0; rg < 16; ++rg) oacc[db][rg] *= corr;
    }

    // p = exp2(s - m); row sum (pairwise); pack P^T fragments in-register
    float sm0[16];
#pragma unroll
    for (int kb = 0; kb < 2; ++kb)
#pragma unroll
      for (int rg = 0; rg < 16; ++rg)
        sacc[kb][rg] = exp2f(sacc[kb][rg] - m_run);
#pragma unroll
    for (int rg = 0; rg < 16; ++rg) sm0[rg] = sacc[0][rg] + sacc[1][rg];
#pragma unroll
    for (int rg = 0; rg < 8; ++rg) sm0[rg] += sm0[rg + 8];
#pragma unroll
    for (int rg = 0; rg < 4; ++rg) sm0[rg] += sm0[rg + 4];
    float sm = (sm0[0] + sm0[1]) + (sm0[2] + sm0[3]);
    sm += __shfl_xor(sm, 32, 64);
    l_run += sm;

    // pack P^T: cvt_pk pairs + permlane32_swap (r7-verified word assembly)
    short8v pa[4];
#pragma unroll
    for (int kb = 0; kb < 2; ++kb) {
      u32 pw00, pw01, pw10, pw11, pw20, pw21, pw30, pw31;
      asm("v_cvt_pk_bf16_f32 %0, %1, %2" : "=v"(pw00) : "v"(sacc[kb][0]), "v"(sacc[kb][1]));
      asm("v_cvt_pk_bf16_f32 %0, %1, %2" : "=v"(pw01) : "v"(sacc[kb][2]), "v"(sacc[kb][3]));
      asm("v_cvt_pk_bf16_f32 %0, %1, %2" : "=v"(pw10) : "v"(sacc[kb][4]), "v"(sacc[kb][5]));
      asm("v_cvt_pk_bf16_f32 %0, %1, %2" : "=v"(pw11) : "v"(sacc[kb][6]), "v"(sacc[kb][7]));
      asm("v_cvt_pk_bf16_f32 %0, %1, %2" : "=v"(pw20) : "v"(sacc[kb][8]), "v"(sacc[kb][9]));
      asm("v_cvt_pk_bf16_f32 %0, %1, %2" : "=v"(pw21) : "v"(sacc[kb][10]), "v"(sacc[kb][11]));
      asm("v_cvt_pk_bf16_f32 %0, %1, %2" : "=v"(pw30) : "v"(sacc[kb][12]), "v"(sacc[kb][13]));
      asm("v_cvt_pk_bf16_f32 %0, %1, %2" : "=v"(pw31) : "v"(sacc[kb][14]), "v"(sacc[kb][15]));
      u32x2 a0 = __builtin_amdgcn_permlane32_swap(pw00, pw10, false, false);
      u32x2 a1 = __builtin_amdgcn_permlane32_swap(pw01, pw11, false, false);
      u32x4 wv0; wv0[0] = a0[0]; wv0[1] = a1[0]; wv0[2] = a0[1]; wv0[3] = a1[1];
      pa[kb * 2 + 0] = __builtin_bit_cast(short8v, wv0);
      u32x2 b0 = __builtin_amdgcn_permlane32_swap(pw20, pw30, false, false);
      u32x2 b1 = __builtin_amdgcn_permlane32_swap(pw21, pw31, false, false);
      u32x4 wv1; wv1[0] = b0[0]; wv1[1] = b1[0]; wv1[2] = b0[1]; wv1[3] = b1[1];
      pa[kb * 2 + 1] = __builtin_bit_cast(short8v, wv1);
    }

    // PV: O^T[d][q] += V^T[d][s] * P^T[s][q]
    __builtin_amdgcn_s_setprio(1);
#pragma unroll
    for (int sc = 0; sc < 4; ++sc) {
#pragma unroll
      for (int db = 0; db < 4; ++db) {
        short8v vf = *(const short8v*)(Vp +
            (size_t)(db * 32 + l31) * 2048 + kv0 + sc * 16 + hb * 8);
        oacc[db] = __builtin_amdgcn_mfma_f32_32x32x16_bf16(vf, pa[sc],
                                                           oacc[db], 0, 0, 0);
      }
    }
    __builtin_amdgcn_s_setprio(0);
  }

  // epilogue: lane-local normalize, pack pairs, store 8B chunks
  const float inv = 1.0f / l_run;
  u16* yp = Y + ((size_t)b * 2048 + qrow) * 2048 + h * 128;
#pragma unroll
  for (int db = 0; db < 4; ++db)
#pragma unroll
    for (int j = 0; j < 4; ++j) {
      float a0 = oacc[db][4 * j] * inv, a1 = oacc[db][4 * j + 1] * inv;
      float a2 = oacc[db][4 * j + 2] * inv, a3 = oacc[db][4 * j + 3] * inv;
      u32 w0, w1;
      asm("v_cvt_pk_bf16_f32 %0, %1, %2" : "=v"(w0) : "v"(a0), "v"(a1));
      asm("v_cvt_pk_bf16_f32 %0, %1, %2" : "=v"(w1) : "v"(a2), "v"(a3));
      *(u32x2*)(yp + db * 32 + 8 * j + 4 * hb) = (u32x2){w0, w1};
    }
}

// ---------------- RMSNorm ----------------
__global__ __launch_bounds__(256) void rmsnorm_k(const u16* __restrict__ Yb,
                                                 const float* __restrict__ nw,
                                                 float* __restrict__ out) {
  const int row = blockIdx.x;
  const int t = threadIdx.x;
  const u16* yr = Yb + (size_t)row * 2048 + t * 8;
  short8v v = *(const short8v*)yr;
  float x[8];
  float ss = 0.f;
#pragma unroll
  for (int j = 0; j < 8; ++j) {
    x[j] = b2f((u16)v[j]);
    ss += x[j] * x[j];
  }
#pragma unroll
  for (int dm = 1; dm < 64; dm <<= 1) ss += __shfl_xor(ss, dm, 64);
  __shared__ float red[4];
  if ((t & 63) == 0) red[t >> 6] = ss;
  __syncthreads();
  float tot = red[0] + red[1] + red[2] + red[3];
  float inv = rsqrtf(tot * (1.0f / 2048.0f) + 1e-6f);
  float* op = out + (size_t)row * 2048 + t * 8;
  const float* wp = nw + t * 8;
  f32x4 o0, o1;
#pragma unroll
  for (int j = 0; j < 4; ++j) o0[j] = x[j] * inv * wp[j];
#pragma unroll
  for (int j = 0; j < 4; ++j) o1[j] = x[4 + j] * inv * wp[4 + j];
  *(f32x4*)op = o0;
  *(f32x4*)(op + 4) = o1;
}

extern "C" void kernel_launch(void* const* d_in, const int* in_sizes, int n_in,
                              void* d_out, int out_size, void* d_ws,
                              size_t ws_size, hipStream_t stream) {
  (void)in_sizes; (void)n_in; (void)out_size; (void)ws_size;
  const float* x = (const float*)d_in[0];
  const float* w_attn = (const float*)d_in[1];
  const float* w_proj = (const float*)d_in[2];
  const float* norm_w = (const float*)d_in[3];
  float* out = (float*)d_out;
  char* ws = (char*)d_ws;

  size_t off = 0;
  auto alloc = [&](size_t n) {
    size_t r = off;
    off += (n + 255) & ~(size_t)255;
    return r;
  };
  u16* xb = (u16*)(ws + alloc(33554432));     // x bf16 [8192][2048]
  u16* wabT = (u16*)(ws + alloc(12582912));   // w_attn^T bf16 [3072][2048]
  u16* qkv = (u16*)(ws + alloc(50331648));    // [8192][3072]
  u16* q_r = (u16*)(ws + alloc(33554432));    // [4][16][2048][128]
  u16* vT = (u16*)(ws + alloc(8388608));      // [4][4][128][2048]
  u16* wpT = (u16*)(ws + alloc(8388608));     // w_proj^T bf16 [2048][2048]
  float* cosT = (float*)(ws + alloc(524288)); // [2048][64]
  float* sinT = (float*)(ws + alloc(524288));
  u16* k_r = wabT;  // reuse (dead after GEMM1)
  u16* y = xb;      // reuse: attn out [8192][2048]
  u16* y2 = qkv;    // reuse: proj out [8192][2048]

  cvt_x_k<<<8192, 256, 0, stream>>>(x, xb);
  transpose_cvt_k<<<dim3(48, 32), 256, 0, stream>>>(w_attn, wabT, 2048, 3072);
  transpose_cvt_k<<<dim3(32, 32), 256, 0, stream>>>(w_proj, wpT, 2048, 2048);
  rope_table_k<<<512, 256, 0, stream>>>(cosT, sinT);
  gemm256_k<<<dim3(12, 32), 512, 0, stream>>>(xb, wabT, qkv, 3072, 2048);
  rope_scatter_k<<<8192, 256, 0, stream>>>(qkv, cosT, sinT, q_r, k_r);
  v_trans_k<<<dim3(32, 2, 16), 256, 0, stream>>>(qkv, vT);
  attn_k<<<dim3(1024), 256, 0, stream>>>(q_r, k_r, vT, y);
  gemm256_k<<<dim3(8, 32), 512, 0, stream>>>(y, wpT, y2, 2048, 2048);
  rmsnorm_k<<<8192, 256, 0, stream>>>(y2, norm_w, out);
}

// Round 12
// 478.351 us; speedup vs baseline: 1.3300x; 1.3300x over previous
//
#include <hip/hip_runtime.h>

#define DEVI __device__ __forceinline__

using u16 = unsigned short;
using u32 = unsigned int;

typedef __attribute__((ext_vector_type(8))) short short8v;
typedef __attribute__((ext_vector_type(4))) float f32x4;
typedef __attribute__((ext_vector_type(16))) float f32x16;
typedef __attribute__((ext_vector_type(2))) u32 u32x2;
typedef __attribute__((ext_vector_type(4))) u32 u32x4;

DEVI u16 f2b(float f) {
  u32 u = __builtin_bit_cast(u32, f);
  u += 0x7fffu + ((u >> 16) & 1u);
  return (u16)(u >> 16);
}
DEVI float b2f(u16 b) { return __builtin_bit_cast(float, (u32)b << 16); }

DEVI void gload16(const void* g, void* l) {
  __builtin_amdgcn_global_load_lds(
      (const __attribute__((address_space(1))) void*)g,
      (__attribute__((address_space(3))) void*)l, 16, 0, 0);
}

// ---------------- x: fp32 -> bf16 ----------------
__global__ __launch_bounds__(256) void cvt_x_k(const float* __restrict__ in,
                                               u16* __restrict__ out) {
  size_t i = ((size_t)blockIdx.x * 256 + threadIdx.x) * 8;
  f32x4 a = *(const f32x4*)(in + i);
  f32x4 c = *(const f32x4*)(in + i + 4);
  short8v o;
  o[0] = (short)f2b(a[0]); o[1] = (short)f2b(a[1]);
  o[2] = (short)f2b(a[2]); o[3] = (short)f2b(a[3]);
  o[4] = (short)f2b(c[0]); o[5] = (short)f2b(c[1]);
  o[6] = (short)f2b(c[2]); o[7] = (short)f2b(c[3]);
  *(short8v*)(out + i) = o;
}

// ---------------- transpose + cvt ----------------
__global__ __launch_bounds__(256) void transpose_cvt_k(
    const float* __restrict__ in, u16* __restrict__ out, int R, int Ccols) {
  __shared__ u16 tile[64][65];
  const int r0 = blockIdx.y * 64, c0 = blockIdx.x * 64;
  const int tx = threadIdx.x & 63, ty = threadIdx.x >> 6;
#pragma unroll
  for (int jj = 0; jj < 16; ++jj) {
    int r = ty + jj * 4;
    tile[r][tx] = f2b(in[(size_t)(r0 + r) * Ccols + c0 + tx]);
  }
  __syncthreads();
#pragma unroll
  for (int jj = 0; jj < 16; ++jj) {
    int c = ty + jj * 4;
    out[(size_t)(c0 + c) * R + r0 + tx] = tile[tx][c];
  }
}

// ---------------- rope table ----------------
__global__ __launch_bounds__(256) void rope_table_k(float* __restrict__ cosT,
                                                    float* __restrict__ sinT) {
  int idx = blockIdx.x * 256 + threadIdx.x;
  int s = idx >> 6, i = idx & 63;
  float inv_freq = expf(-(float)i * (1.0f / 64.0f) * 9.210340371976184f);
  float ang = (float)s * inv_freq;
  cosT[idx] = cosf(ang);
  sinT[idx] = sinf(ang);
}

// ---------------- rope + scatter q,k (q pre-scaled by 1/sqrt(hd)*log2e) ----
__global__ __launch_bounds__(256) void rope_scatter_k(
    const u16* __restrict__ qkv, const float* __restrict__ cosT,
    const float* __restrict__ sinT, u16* __restrict__ q_r,
    u16* __restrict__ k_r) {
  const float QS = 0.08838834764831845f * 1.4426950408889634f;
  const int row = blockIdx.x;
  const int b = row >> 11, s = row & 2047;
  const u16* in = qkv + (size_t)row * 3072;
  const float* cp = cosT + s * 64;
  const float* sp = sinT + s * 64;
  for (int p = threadIdx.x; p < 1280; p += 256) {
    int f0 = p * 2;
    u32 pair = *(const u32*)(in + f0);
    float x0 = b2f((u16)(pair & 0xffffu));
    float x1 = b2f((u16)(pair >> 16));
    int d, head;
    u16* dst;
    bool isq = (f0 < 2048);
    if (isq) {
      head = f0 >> 7; d = f0 & 127;
      dst = q_r + (((size_t)(b * 16 + head)) * 2048 + s) * 128 + d;
    } else {
      int idx = f0 - 2048;
      head = idx >> 7; d = idx & 127;
      dst = k_r + (((size_t)(b * 4 + head)) * 2048 + s) * 128 + d;
    }
    int i = d >> 1;
    float c = cp[i], sn = sp[i];
    float o0 = x0 * c - x1 * sn;
    float o1 = x0 * sn + x1 * c;
    if (isq) { o0 *= QS; o1 *= QS; }
    *(u32*)dst = (u32)f2b(o0) | ((u32)f2b(o1) << 16);
  }
}

// ---------------- v transpose ----------------
__global__ __launch_bounds__(256) void v_trans_k(const u16* __restrict__ qkv,
                                                 u16* __restrict__ vT) {
  __shared__ u16 tile[64][65];
  const int s0 = blockIdx.x * 64, d0 = blockIdx.y * 64;
  const int bk = blockIdx.z;
  const int b = bk >> 2, kh = bk & 3;
  const int tx = threadIdx.x & 63, ty = threadIdx.x >> 6;
  const u16* src = qkv + ((size_t)b * 2048) * 3072 + 2560 + kh * 128;
#pragma unroll
  for (int jj = 0; jj < 16; ++jj) {
    int s = ty + jj * 4;
    tile[s][tx] = src[(size_t)(s0 + s) * 3072 + d0 + tx];
  }
  __syncthreads();
  u16* dst = vT + (((size_t)bk * 128 + d0) * 2048) + s0;
#pragma unroll
  for (int jj = 0; jj < 16; ++jj) {
    int dd = ty + jj * 4;
    dst[(size_t)dd * 2048 + tx] = tile[tx][dd];
  }
}

// ---------------- 256x256 8-phase GEMM ----------------
DEVI short8v ldf(const char* half, int r, int slot) {
  return *(const short8v*)(half + r * 64 + (((slot) ^ (r & 3)) << 4));
}

DEVI void stg(const u16* __restrict__ G, int row0, int Kd, int T, int kh,
              char* dst, int t, int w) {
#pragma unroll
  for (int i = 0; i < 2; ++i) {
    int off = i * 8192 + t * 16;
    int r = off >> 6;
    int gs = ((off >> 4) & 3) ^ (r & 3);
    gload16((const char*)G +
                (((size_t)(row0 + r) * Kd) + T * 64 + kh * 32 + gs * 8) * 2,
            dst + i * 8192 + w * 1024);
  }
}

#define VM4 asm volatile("s_waitcnt vmcnt(4)" ::: "memory")
#define PH(P2, KS, CH, STAGE_STMT, TAILWAIT)                                   \
  {                                                                            \
    if ((CH) == 0) {                                                           \
      _Pragma("unroll") for (int mt = 0; mt < 8; ++mt) af[mt] =                \
          ldf(Ab + (P2) * 32768 + (KS) * 16384, wm * 128 + mt * 16 + lo, hi);  \
    }                                                                          \
    bf0 = ldf(Bb + (P2) * 32768 + (KS) * 16384, wn * 64 + (CH) * 32 + lo, hi);\
    bf1 = ldf(Bb + (P2) * 32768 + (KS) * 16384,                                \
              wn * 64 + (CH) * 32 + 16 + lo, hi);                              \
    STAGE_STMT;                                                                \
    __builtin_amdgcn_sched_barrier(0);                                         \
    __builtin_amdgcn_s_barrier();                                              \
    asm volatile("s_waitcnt lgkmcnt(0)" ::: "memory");                         \
    __builtin_amdgcn_sched_barrier(0);                                         \
    __builtin_amdgcn_s_setprio(1);                                             \
    _Pragma("unroll") for (int mt = 0; mt < 8; ++mt) {                         \
      acc[mt][(CH) * 2] = __builtin_amdgcn_mfma_f32_16x16x32_bf16(             \
          af[mt], bf0, acc[mt][(CH) * 2], 0, 0, 0);                            \
      acc[mt][(CH) * 2 + 1] = __builtin_amdgcn_mfma_f32_16x16x32_bf16(         \
          af[mt], bf1, acc[mt][(CH) * 2 + 1], 0, 0, 0);                        \
    }                                                                          \
    __builtin_amdgcn_s_setprio(0);                                             \
    TAILWAIT;                                                                  \
    __builtin_amdgcn_sched_barrier(0);                                         \
    __builtin_amdgcn_s_barrier();                                              \
    __builtin_amdgcn_sched_barrier(0);                                         \
  }

__global__ __launch_bounds__(512, 2) void gemm256_k(const u16* __restrict__ A,
                                                    const u16* __restrict__ BT,
                                                    u16* __restrict__ C, int N,
                                                    int Kd) {
  __shared__ __align__(16) char lds[131072];
  char* Ab = lds;
  char* Bb = lds + 65536;

  const int t = threadIdx.x;
  const int lane = t & 63, lo = lane & 15, hi = lane >> 4;
  const int w = t >> 6, wm = w >> 2, wn = w & 3;

  const int ntx = gridDim.x;
  const int nwg = ntx * gridDim.y;
  const int orig = blockIdx.y * ntx + blockIdx.x;
  const int cpx = nwg >> 3;
  const int swz = (orig & 7) * cpx + (orig >> 3);
  const int m0 = (swz / ntx) * 256, n0 = (swz % ntx) * 256;

  f32x4 acc[8][4];
#pragma unroll
  for (int a = 0; a < 8; ++a)
#pragma unroll
    for (int c = 0; c < 4; ++c) acc[a][c] = (f32x4){0.f, 0.f, 0.f, 0.f};

  short8v af[8], bf0, bf1;

  const int NK = Kd >> 6;
  const int NK2 = NK >> 1;

  stg(A, m0, Kd, 0, 0, Ab + 0, t, w);
  stg(BT, n0, Kd, 0, 0, Bb + 0, t, w);
  stg(A, m0, Kd, 0, 1, Ab + 16384, t, w);
  stg(BT, n0, Kd, 0, 1, Bb + 16384, t, w);
  stg(A, m0, Kd, 1, 0, Ab + 32768, t, w);
  stg(BT, n0, Kd, 1, 0, Bb + 32768, t, w);
  VM4;
  __builtin_amdgcn_sched_barrier(0);
  __builtin_amdgcn_s_barrier();
  __builtin_amdgcn_sched_barrier(0);

  for (int kt2 = 0; kt2 < NK2; ++kt2) {
    int T1v = 2 * kt2 + 1;
    int T2v = 2 * kt2 + 2; if (T2v > NK - 1) T2v = NK - 1;
    int T3v = 2 * kt2 + 3; if (T3v > NK - 1) T3v = NK - 1;
    PH(0, 0, 0, stg(A, m0, Kd, T1v, 1, Ab + 49152, t, w), (void)0);
    PH(0, 0, 1, stg(BT, n0, Kd, T1v, 1, Bb + 49152, t, w), (void)0);
    PH(0, 1, 0, stg(A, m0, Kd, T2v, 0, Ab + 0, t, w), (void)0);
    PH(0, 1, 1, stg(BT, n0, Kd, T2v, 0, Bb + 0, t, w), VM4);
    PH(1, 0, 0, stg(A, m0, Kd, T2v, 1, Ab + 16384, t, w), (void)0);
    PH(1, 0, 1, stg(BT, n0, Kd, T2v, 1, Bb + 16384, t, w), (void)0);
    PH(1, 1, 0, stg(A, m0, Kd, T3v, 0, Ab + 32768, t, w), (void)0);
    PH(1, 1, 1, stg(BT, n0, Kd, T3v, 0, Bb + 32768, t, w), VM4);
  }
  asm volatile("s_waitcnt vmcnt(0)" ::: "memory");

#pragma unroll
  for (int mt = 0; mt < 8; ++mt)
#pragma unroll
    for (int nt = 0; nt < 4; ++nt)
#pragma unroll
      for (int r = 0; r < 4; ++r) {
        int row = m0 + wm * 128 + mt * 16 + hi * 4 + r;
        int col = n0 + wn * 64 + nt * 16 + lo;
        C[(size_t)row * N + col] = f2b(acc[mt][nt][r]);
      }
}

// ---------------- flash attention: 32x32 MFMA, KVBLK=128 ----------------
// r7 structure (best measured) with doubled KV tile: halves iteration count,
// barriers, and drains per key; 4 independent kb-streams of QK/softmax ILP.
// K,V double-buffered 2x32KB each (128KB, 1 block/CU). K and V tiles share
// the identical 256B-row/16-slot/&7-involution layout.
__global__ __launch_bounds__(256, 1) void attn_k(const u16* __restrict__ Q,
                                                 const u16* __restrict__ K,
                                                 const u16* __restrict__ VT,
                                                 u16* __restrict__ Y) {
  __shared__ __align__(16) u16 lK[2][128 * 128];
  __shared__ __align__(16) u16 lV[2][128 * 128];

  const int t = threadIdx.x;
  const int lane = t & 63;
  const int l31 = lane & 31, hb = lane >> 5;
  const int w = t >> 6;

  const int id = blockIdx.x;
  const int xcd = id & 7, pos = id >> 3;
  const int bh = xcd + ((pos >> 4) << 3);
  const int qt = 15 - (pos & 15);  // heavy q-tiles first
  const int b = bh >> 4, h = bh & 15, kh = h >> 2;

  const size_t qbase = (size_t)(b * 16 + h) * 2048 * 128;
  const size_t kbase = (size_t)(b * 4 + kh) * 2048 * 128;
  const size_t vbase = (size_t)(b * 4 + kh) * 128 * 2048;

  const int q0 = qt * 128;
  const int qrow = q0 + w * 32 + l31;

  // Q fragments: B-operand, q = lane&31, d = j16*16 + hb*8 + e
  short8v qf[8];
#pragma unroll
  for (int j16 = 0; j16 < 8; ++j16)
    qf[j16] = *(const short8v*)(Q + qbase + (size_t)qrow * 128 + j16 * 16 + hb * 8);

  float m_run = -3.0e38f, l_run = 0.f;
  f32x16 oacc[4];
#pragma unroll
  for (int db = 0; db < 4; ++db)
#pragma unroll
    for (int rg = 0; rg < 16; ++rg) oacc[db][rg] = 0.f;

  const int ntile = qt + 1;  // 128-key tiles

  auto stage = [&](int buf, int j) {
    const int kv0 = j * 128;
#pragma unroll
    for (int i = 0; i < 8; ++i) {
      int off = i * 4096 + t * 16;
      int r = off >> 8;               // key row, 256B rows
      int sl = (off >> 4) & 15;
      int gs = sl ^ (r & 7);
      gload16((const char*)K + (kbase + (size_t)(kv0 + r) * 128 + gs * 8) * 2,
              (char*)lK[buf] + i * 4096 + w * 1024);
    }
#pragma unroll
    for (int i = 0; i < 8; ++i) {
      int off = i * 4096 + t * 16;
      int r = off >> 8;               // d row, 256B segment of the 2048-row
      int sl = (off >> 4) & 15;
      int gs = sl ^ (r & 7);
      gload16((const char*)VT + (vbase + (size_t)r * 2048 + kv0 + gs * 8) * 2,
              (char*)lV[buf] + i * 4096 + w * 1024);
    }
  };

  stage(0, 0);
  asm volatile("s_waitcnt vmcnt(0)" ::: "memory");
  __builtin_amdgcn_sched_barrier(0);
  __builtin_amdgcn_s_barrier();
  __builtin_amdgcn_sched_barrier(0);

  for (int jj = 0; jj < ntile; ++jj) {
    const int cur = jj & 1;
    if (jj + 1 < ntile) stage(cur ^ 1, jj + 1);

    const char* lKc = (const char*)lK[cur];
    const char* lVc = (const char*)lV[cur];
    const int kv0 = jj * 128;

    // QK^T: S^T[k][q], k = kv0 + kb*32 + (rg&3)+8*(rg>>2)+4*hb, q = qrow
    f32x16 sacc[4];
#pragma unroll
    for (int kb = 0; kb < 4; ++kb)
#pragma unroll
      for (int rg = 0; rg < 16; ++rg) sacc[kb][rg] = 0.f;

    __builtin_amdgcn_s_setprio(1);
#pragma unroll
    for (int j16 = 0; j16 < 8; ++j16) {
      const int c = j16 * 2 + hb;
#pragma unroll
      for (int kb = 0; kb < 4; ++kb) {
        int kr = kb * 32 + l31;
        short8v kf = *(const short8v*)(lKc + kr * 256 + ((c ^ (kr & 7)) << 4));
        sacc[kb] = __builtin_amdgcn_mfma_f32_32x32x16_bf16(kf, qf[j16],
                                                           sacc[kb], 0, 0, 0);
      }
    }
    __builtin_amdgcn_s_setprio(0);

    // causal mask (final tile covers the diagonal 128-block)
    if (jj == ntile - 1) {
      const int mb = kv0 + 4 * hb - qrow;
#pragma unroll
      for (int kb = 0; kb < 4; ++kb)
#pragma unroll
        for (int rg = 0; rg < 16; ++rg)
          if (mb + kb * 32 + (rg & 3) + 8 * (rg >> 2) > 0)
            sacc[kb][rg] = -1.0e38f;
    }

    // row max: pairwise tree + 1 cross-half shfl
    float mt0[16];
#pragma unroll
    for (int rg = 0; rg < 16; ++rg)
      mt0[rg] = fmaxf(fmaxf(sacc[0][rg], sacc[1][rg]),
                      fmaxf(sacc[2][rg], sacc[3][rg]));
#pragma unroll
    for (int rg = 0; rg < 8; ++rg) mt0[rg] = fmaxf(mt0[rg], mt0[rg + 8]);
#pragma unroll
    for (int rg = 0; rg < 4; ++rg) mt0[rg] = fmaxf(mt0[rg], mt0[rg + 4]);
    float mx = fmaxf(fmaxf(mt0[0], mt0[1]), fmaxf(mt0[2], mt0[3]));
    mx = fmaxf(mx, __shfl_xor(mx, 32, 64));

    // defer-max rescale
    if (__any(mx > m_run + 8.f)) {
      float mn = fmaxf(m_run, mx);
      float corr = exp2f(m_run - mn);
      m_run = mn;
      l_run *= corr;
#pragma unroll
      for (int db = 0; db < 4; ++db)
#pragma unroll
        for (int rg = 0; rg < 16; ++rg) oacc[db][rg] *= corr;
    }

    // p = exp2(s - m); row sum (pairwise); pack P^T fragments in-register
    float sm0[16];
#pragma unroll
    for (int kb = 0; kb < 4; ++kb)
#pragma unroll
      for (int rg = 0; rg < 16; ++rg)
        sacc[kb][rg] = exp2f(sacc[kb][rg] - m_run);
#pragma unroll
    for (int rg = 0; rg < 16; ++rg)
      sm0[rg] = (sacc[0][rg] + sacc[1][rg]) + (sacc[2][rg] + sacc[3][rg]);
#pragma unroll
    for (int rg = 0; rg < 8; ++rg) sm0[rg] += sm0[rg + 8];
#pragma unroll
    for (int rg = 0; rg < 4; ++rg) sm0[rg] += sm0[rg + 4];
    float sm = (sm0[0] + sm0[1]) + (sm0[2] + sm0[3]);
    sm += __shfl_xor(sm, 32, 64);
    l_run += sm;

    // pack P^T: cvt_pk pairs + permlane32_swap (r7-verified word assembly)
    short8v pa[8];
#pragma unroll
    for (int kb = 0; kb < 4; ++kb) {
      u32 pw00, pw01, pw10, pw11, pw20, pw21, pw30, pw31;
      asm("v_cvt_pk_bf16_f32 %0, %1, %2" : "=v"(pw00) : "v"(sacc[kb][0]), "v"(sacc[kb][1]));
      asm("v_cvt_pk_bf16_f32 %0, %1, %2" : "=v"(pw01) : "v"(sacc[kb][2]), "v"(sacc[kb][3]));
      asm("v_cvt_pk_bf16_f32 %0, %1, %2" : "=v"(pw10) : "v"(sacc[kb][4]), "v"(sacc[kb][5]));
      asm("v_cvt_pk_bf16_f32 %0, %1, %2" : "=v"(pw11) : "v"(sacc[kb][6]), "v"(sacc[kb][7]));
      asm("v_cvt_pk_bf16_f32 %0, %1, %2" : "=v"(pw20) : "v"(sacc[kb][8]), "v"(sacc[kb][9]));
      asm("v_cvt_pk_bf16_f32 %0, %1, %2" : "=v"(pw21) : "v"(sacc[kb][10]), "v"(sacc[kb][11]));
      asm("v_cvt_pk_bf16_f32 %0, %1, %2" : "=v"(pw30) : "v"(sacc[kb][12]), "v"(sacc[kb][13]));
      asm("v_cvt_pk_bf16_f32 %0, %1, %2" : "=v"(pw31) : "v"(sacc[kb][14]), "v"(sacc[kb][15]));
      u32x2 a0 = __builtin_amdgcn_permlane32_swap(pw00, pw10, false, false);
      u32x2 a1 = __builtin_amdgcn_permlane32_swap(pw01, pw11, false, false);
      u32x4 wv0; wv0[0] = a0[0]; wv0[1] = a1[0]; wv0[2] = a0[1]; wv0[3] = a1[1];
      pa[kb * 2 + 0] = __builtin_bit_cast(short8v, wv0);
      u32x2 b0 = __builtin_amdgcn_permlane32_swap(pw20, pw30, false, false);
      u32x2 b1 = __builtin_amdgcn_permlane32_swap(pw21, pw31, false, false);
      u32x4 wv1; wv1[0] = b0[0]; wv1[1] = b1[0]; wv1[2] = b0[1]; wv1[3] = b1[1];
      pa[kb * 2 + 1] = __builtin_bit_cast(short8v, wv1);
    }

    // PV: O^T[d][q] += V^T[d][s] * P^T[s][q], 128 keys
    __builtin_amdgcn_s_setprio(1);
#pragma unroll
    for (int sc = 0; sc < 8; ++sc) {
      const int c = sc * 2 + hb;
#pragma unroll
      for (int db = 0; db < 4; ++db) {
        int vr = db * 32 + l31;
        short8v vf = *(const short8v*)(lVc + vr * 256 + (((c & 15) ^ (vr & 7)) << 4));
        oacc[db] = __builtin_amdgcn_mfma_f32_32x32x16_bf16(vf, pa[sc],
                                                           oacc[db], 0, 0, 0);
      }
    }
    __builtin_amdgcn_s_setprio(0);

    asm volatile("s_waitcnt vmcnt(0)" ::: "memory");
    __builtin_amdgcn_sched_barrier(0);
    __builtin_amdgcn_s_barrier();
    __builtin_amdgcn_sched_barrier(0);
  }

  // epilogue: lane-local normalize, pack pairs, store 8B chunks
  const float inv = 1.0f / l_run;
  u16* yp = Y + ((size_t)b * 2048 + qrow) * 2048 + h * 128;
#pragma unroll
  for (int db = 0; db < 4; ++db)
#pragma unroll
    for (int j = 0; j < 4; ++j) {
      float a0 = oacc[db][4 * j] * inv, a1 = oacc[db][4 * j + 1] * inv;
      float a2 = oacc[db][4 * j + 2] * inv, a3 = oacc[db][4 * j + 3] * inv;
      u32 w0, w1;
      asm("v_cvt_pk_bf16_f32 %0, %1, %2" : "=v"(w0) : "v"(a0), "v"(a1));
      asm("v_cvt_pk_bf16_f32 %0, %1, %2" : "=v"(w1) : "v"(a2), "v"(a3));
      *(u32x2*)(yp + db * 32 + 8 * j + 4 * hb) = (u32x2){w0, w1};
    }
}

// ---------------- RMSNorm ----------------
__global__ __launch_bounds__(256) void rmsnorm_k(const u16* __restrict__ Yb,
                                                 const float* __restrict__ nw,
                                                 float* __restrict__ out) {
  const int row = blockIdx.x;
  const int t = threadIdx.x;
  const u16* yr = Yb + (size_t)row * 2048 + t * 8;
  short8v v = *(const short8v*)yr;
  float x[8];
  float ss = 0.f;
#pragma unroll
  for (int j = 0; j < 8; ++j) {
    x[j] = b2f((u16)v[j]);
    ss += x[j] * x[j];
  }
#pragma unroll
  for (int dm = 1; dm < 64; dm <<= 1) ss += __shfl_xor(ss, dm, 64);
  __shared__ float red[4];
  if ((t & 63) == 0) red[t >> 6] = ss;
  __syncthreads();
  float tot = red[0] + red[1] + red[2] + red[3];
  float inv = rsqrtf(tot * (1.0f / 2048.0f) + 1e-6f);
  float* op = out + (size_t)row * 2048 + t * 8;
  const float* wp = nw + t * 8;
  f32x4 o0, o1;
#pragma unroll
  for (int j = 0; j < 4; ++j) o0[j] = x[j] * inv * wp[j];
#pragma unroll
  for (int j = 0; j < 4; ++j) o1[j] = x[4 + j] * inv * wp[4 + j];
  *(f32x4*)op = o0;
  *(f32x4*)(op + 4) = o1;
}

extern "C" void kernel_launch(void* const* d_in, const int* in_sizes, int n_in,
                              void* d_out, int out_size, void* d_ws,
                              size_t ws_size, hipStream_t stream) {
  (void)in_sizes; (void)n_in; (void)out_size; (void)ws_size;
  const float* x = (const float*)d_in[0];
  const float* w_attn = (const float*)d_in[1];
  const float* w_proj = (const float*)d_in[2];
  const float* norm_w = (const float*)d_in[3];
  float* out = (float*)d_out;
  char* ws = (char*)d_ws;

  size_t off = 0;
  auto alloc = [&](size_t n) {
    size_t r = off;
    off += (n + 255) & ~(size_t)255;
    return r;
  };
  u16* xb = (u16*)(ws + alloc(33554432));     // x bf16 [8192][2048]
  u16* wabT = (u16*)(ws + alloc(12582912));   // w_attn^T bf16 [3072][2048]
  u16* qkv = (u16*)(ws + alloc(50331648));    // [8192][3072]
  u16* q_r = (u16*)(ws + alloc(33554432));    // [4][16][2048][128]
  u16* vT = (u16*)(ws + alloc(8388608));      // [4][4][128][2048]
  u16* wpT = (u16*)(ws + alloc(8388608));     // w_proj^T bf16 [2048][2048]
  float* cosT = (float*)(ws + alloc(524288)); // [2048][64]
  float* sinT = (float*)(ws + alloc(524288));
  u16* k_r = wabT;  // reuse (dead after GEMM1)
  u16* y = xb;      // reuse: attn out [8192][2048]
  u16* y2 = qkv;    // reuse: proj out [8192][2048]

  cvt_x_k<<<8192, 256, 0, stream>>>(x, xb);
  transpose_cvt_k<<<dim3(48, 32), 256, 0, stream>>>(w_attn, wabT, 2048, 3072);
  transpose_cvt_k<<<dim3(32, 32), 256, 0, stream>>>(w_proj, wpT, 2048, 2048);
  rope_table_k<<<512, 256, 0, stream>>>(cosT, sinT);
  gemm256_k<<<dim3(12, 32), 512, 0, stream>>>(xb, wabT, qkv, 3072, 2048);
  rope_scatter_k<<<8192, 256, 0, stream>>>(qkv, cosT, sinT, q_r, k_r);
  v_trans_k<<<dim3(32, 2, 16), 256, 0, stream>>>(qkv, vT);
  attn_k<<<dim3(1024), 256, 0, stream>>>(q_r, k_r, vT, y);
  gemm256_k<<<dim3(8, 32), 512, 0, stream>>>(y, wpT, y2, 2048, 2048);
  rmsnorm_k<<<8192, 256, 0, stream>>>(y2, norm_w, out);
}

// Round 13
// 414.663 us; speedup vs baseline: 1.5343x; 1.1536x over previous
//
#include <hip/hip_runtime.h>

#define DEVI __device__ __forceinline__

using u16 = unsigned short;
using u32 = unsigned int;

typedef __attribute__((ext_vector_type(8))) short short8v;
typedef __attribute__((ext_vector_type(4))) float f32x4;
typedef __attribute__((ext_vector_type(16))) float f32x16;
typedef __attribute__((ext_vector_type(2))) u32 u32x2;
typedef __attribute__((ext_vector_type(4))) u32 u32x4;

DEVI u16 f2b(float f) {
  u32 u = __builtin_bit_cast(u32, f);
  u += 0x7fffu + ((u >> 16) & 1u);
  return (u16)(u >> 16);
}
DEVI float b2f(u16 b) { return __builtin_bit_cast(float, (u32)b << 16); }

DEVI void gload16(const void* g, void* l) {
  __builtin_amdgcn_global_load_lds(
      (const __attribute__((address_space(1))) void*)g,
      (__attribute__((address_space(3))) void*)l, 16, 0, 0);
}

// ---------------- x: fp32 -> bf16 ----------------
__global__ __launch_bounds__(256) void cvt_x_k(const float* __restrict__ in,
                                               u16* __restrict__ out) {
  size_t i = ((size_t)blockIdx.x * 256 + threadIdx.x) * 8;
  f32x4 a = *(const f32x4*)(in + i);
  f32x4 c = *(const f32x4*)(in + i + 4);
  short8v o;
  o[0] = (short)f2b(a[0]); o[1] = (short)f2b(a[1]);
  o[2] = (short)f2b(a[2]); o[3] = (short)f2b(a[3]);
  o[4] = (short)f2b(c[0]); o[5] = (short)f2b(c[1]);
  o[6] = (short)f2b(c[2]); o[7] = (short)f2b(c[3]);
  *(short8v*)(out + i) = o;
}

// ---------------- transpose + cvt ----------------
__global__ __launch_bounds__(256) void transpose_cvt_k(
    const float* __restrict__ in, u16* __restrict__ out, int R, int Ccols) {
  __shared__ u16 tile[64][65];
  const int r0 = blockIdx.y * 64, c0 = blockIdx.x * 64;
  const int tx = threadIdx.x & 63, ty = threadIdx.x >> 6;
#pragma unroll
  for (int jj = 0; jj < 16; ++jj) {
    int r = ty + jj * 4;
    tile[r][tx] = f2b(in[(size_t)(r0 + r) * Ccols + c0 + tx]);
  }
  __syncthreads();
#pragma unroll
  for (int jj = 0; jj < 16; ++jj) {
    int c = ty + jj * 4;
    out[(size_t)(c0 + c) * R + r0 + tx] = tile[tx][c];
  }
}

// ---------------- rope table ----------------
__global__ __launch_bounds__(256) void rope_table_k(float* __restrict__ cosT,
                                                    float* __restrict__ sinT) {
  int idx = blockIdx.x * 256 + threadIdx.x;
  int s = idx >> 6, i = idx & 63;
  float inv_freq = expf(-(float)i * (1.0f / 64.0f) * 9.210340371976184f);
  float ang = (float)s * inv_freq;
  cosT[idx] = cosf(ang);
  sinT[idx] = sinf(ang);
}

// ---- fused: rope+scatter q,k (blocks 0..8191) + v transpose (8192..9215) ---
__global__ __launch_bounds__(256) void scatter_vtrans_k(
    const u16* __restrict__ qkv, const float* __restrict__ cosT,
    const float* __restrict__ sinT, u16* __restrict__ q_r,
    u16* __restrict__ k_r, u16* __restrict__ vT) {
  __shared__ u16 tile[64][65];
  const int id = blockIdx.x;
  if (id < 8192) {
    // rope + scatter (q pre-scaled by 1/sqrt(hd)*log2e)
    const float QS = 0.08838834764831845f * 1.4426950408889634f;
    const int b = id >> 11, s = id & 2047;
    const u16* in = qkv + (size_t)id * 3072;
    const float* cp = cosT + s * 64;
    const float* sp = sinT + s * 64;
    for (int p = threadIdx.x; p < 1280; p += 256) {
      int f0 = p * 2;
      u32 pair = *(const u32*)(in + f0);
      float x0 = b2f((u16)(pair & 0xffffu));
      float x1 = b2f((u16)(pair >> 16));
      int d, head;
      u16* dst;
      bool isq = (f0 < 2048);
      if (isq) {
        head = f0 >> 7; d = f0 & 127;
        dst = q_r + (((size_t)(b * 16 + head)) * 2048 + s) * 128 + d;
      } else {
        int idx = f0 - 2048;
        head = idx >> 7; d = idx & 127;
        dst = k_r + (((size_t)(b * 4 + head)) * 2048 + s) * 128 + d;
      }
      int i = d >> 1;
      float c = cp[i], sn = sp[i];
      float o0 = x0 * c - x1 * sn;
      float o1 = x0 * sn + x1 * c;
      if (isq) { o0 *= QS; o1 *= QS; }
      *(u32*)dst = (u32)f2b(o0) | ((u32)f2b(o1) << 16);
    }
  } else {
    // v transpose: vT[b][kh][d][s]
    const int vid = id - 8192;
    const int s0 = (vid & 31) * 64, d0 = ((vid >> 5) & 1) * 64;
    const int bk = vid >> 6;
    const int b = bk >> 2, kh = bk & 3;
    const int tx = threadIdx.x & 63, ty = threadIdx.x >> 6;
    const u16* src = qkv + ((size_t)b * 2048) * 3072 + 2560 + kh * 128;
#pragma unroll
    for (int jj = 0; jj < 16; ++jj) {
      int s = ty + jj * 4;
      tile[s][tx] = src[(size_t)(s0 + s) * 3072 + d0 + tx];
    }
    __syncthreads();
    u16* dst = vT + (((size_t)bk * 128 + d0) * 2048) + s0;
#pragma unroll
    for (int jj = 0; jj < 16; ++jj) {
      int dd = ty + jj * 4;
      dst[(size_t)dd * 2048 + tx] = tile[tx][dd];
    }
  }
}

// ---------------- 256x256 8-phase GEMM ----------------
DEVI short8v ldf(const char* half, int r, int slot) {
  return *(const short8v*)(half + r * 64 + (((slot) ^ (r & 3)) << 4));
}

DEVI void stg(const u16* __restrict__ G, int row0, int Kd, int T, int kh,
              char* dst, int t, int w) {
#pragma unroll
  for (int i = 0; i < 2; ++i) {
    int off = i * 8192 + t * 16;
    int r = off >> 6;
    int gs = ((off >> 4) & 3) ^ (r & 3);
    gload16((const char*)G +
                (((size_t)(row0 + r) * Kd) + T * 64 + kh * 32 + gs * 8) * 2,
            dst + i * 8192 + w * 1024);
  }
}

#define VM4 asm volatile("s_waitcnt vmcnt(4)" ::: "memory")
#define PH(P2, KS, CH, STAGE_STMT, TAILWAIT)                                   \
  {                                                                            \
    if ((CH) == 0) {                                                           \
      _Pragma("unroll") for (int mt = 0; mt < 8; ++mt) af[mt] =                \
          ldf(Ab + (P2) * 32768 + (KS) * 16384, wm * 128 + mt * 16 + lo, hi);  \
    }                                                                          \
    bf0 = ldf(Bb + (P2) * 32768 + (KS) * 16384, wn * 64 + (CH) * 32 + lo, hi);\
    bf1 = ldf(Bb + (P2) * 32768 + (KS) * 16384,                                \
              wn * 64 + (CH) * 32 + 16 + lo, hi);                              \
    STAGE_STMT;                                                                \
    __builtin_amdgcn_sched_barrier(0);                                         \
    __builtin_amdgcn_s_barrier();                                              \
    asm volatile("s_waitcnt lgkmcnt(0)" ::: "memory");                         \
    __builtin_amdgcn_sched_barrier(0);                                         \
    __builtin_amdgcn_s_setprio(1);                                             \
    _Pragma("unroll") for (int mt = 0; mt < 8; ++mt) {                         \
      acc[mt][(CH) * 2] = __builtin_amdgcn_mfma_f32_16x16x32_bf16(             \
          af[mt], bf0, acc[mt][(CH) * 2], 0, 0, 0);                            \
      acc[mt][(CH) * 2 + 1] = __builtin_amdgcn_mfma_f32_16x16x32_bf16(         \
          af[mt], bf1, acc[mt][(CH) * 2 + 1], 0, 0, 0);                        \
    }                                                                          \
    __builtin_amdgcn_s_setprio(0);                                             \
    TAILWAIT;                                                                  \
    __builtin_amdgcn_sched_barrier(0);                                         \
    __builtin_amdgcn_s_barrier();                                              \
    __builtin_amdgcn_sched_barrier(0);                                         \
  }

__global__ __launch_bounds__(512, 2) void gemm256_k(const u16* __restrict__ A,
                                                    const u16* __restrict__ BT,
                                                    u16* __restrict__ C, int N,
                                                    int Kd) {
  __shared__ __align__(16) char lds[131072];
  char* Ab = lds;
  char* Bb = lds + 65536;

  const int t = threadIdx.x;
  const int lane = t & 63, lo = lane & 15, hi = lane >> 4;
  const int w = t >> 6, wm = w >> 2, wn = w & 3;

  const int ntx = gridDim.x;
  const int nwg = ntx * gridDim.y;
  const int orig = blockIdx.y * ntx + blockIdx.x;
  const int cpx = nwg >> 3;
  const int swz = (orig & 7) * cpx + (orig >> 3);
  const int m0 = (swz / ntx) * 256, n0 = (swz % ntx) * 256;

  f32x4 acc[8][4];
#pragma unroll
  for (int a = 0; a < 8; ++a)
#pragma unroll
    for (int c = 0; c < 4; ++c) acc[a][c] = (f32x4){0.f, 0.f, 0.f, 0.f};

  short8v af[8], bf0, bf1;

  const int NK = Kd >> 6;
  const int NK2 = NK >> 1;

  stg(A, m0, Kd, 0, 0, Ab + 0, t, w);
  stg(BT, n0, Kd, 0, 0, Bb + 0, t, w);
  stg(A, m0, Kd, 0, 1, Ab + 16384, t, w);
  stg(BT, n0, Kd, 0, 1, Bb + 16384, t, w);
  stg(A, m0, Kd, 1, 0, Ab + 32768, t, w);
  stg(BT, n0, Kd, 1, 0, Bb + 32768, t, w);
  VM4;
  __builtin_amdgcn_sched_barrier(0);
  __builtin_amdgcn_s_barrier();
  __builtin_amdgcn_sched_barrier(0);

  for (int kt2 = 0; kt2 < NK2; ++kt2) {
    int T1v = 2 * kt2 + 1;
    int T2v = 2 * kt2 + 2; if (T2v > NK - 1) T2v = NK - 1;
    int T3v = 2 * kt2 + 3; if (T3v > NK - 1) T3v = NK - 1;
    PH(0, 0, 0, stg(A, m0, Kd, T1v, 1, Ab + 49152, t, w), (void)0);
    PH(0, 0, 1, stg(BT, n0, Kd, T1v, 1, Bb + 49152, t, w), (void)0);
    PH(0, 1, 0, stg(A, m0, Kd, T2v, 0, Ab + 0, t, w), (void)0);
    PH(0, 1, 1, stg(BT, n0, Kd, T2v, 0, Bb + 0, t, w), VM4);
    PH(1, 0, 0, stg(A, m0, Kd, T2v, 1, Ab + 16384, t, w), (void)0);
    PH(1, 0, 1, stg(BT, n0, Kd, T2v, 1, Bb + 16384, t, w), (void)0);
    PH(1, 1, 0, stg(A, m0, Kd, T3v, 0, Ab + 32768, t, w), (void)0);
    PH(1, 1, 1, stg(BT, n0, Kd, T3v, 0, Bb + 32768, t, w), VM4);
  }
  asm volatile("s_waitcnt vmcnt(0)" ::: "memory");

#pragma unroll
  for (int mt = 0; mt < 8; ++mt)
#pragma unroll
    for (int nt = 0; nt < 4; ++nt)
#pragma unroll
      for (int r = 0; r < 4; ++r) {
        int row = m0 + wm * 128 + mt * 16 + hi * 4 + r;
        int col = n0 + wn * 64 + nt * 16 + lo;
        C[(size_t)row * N + col] = f2b(acc[mt][nt][r]);
      }
}

// ---------------- flash attention: 32x32 MFMA, in-register P (r7 best) ------
// Swapped operands: S^T = mfma(K, Q) -> q on lane&31 (lane-local softmax);
// O^T = mfma(V^T, P^T) -> q on lane&31 again. P^T built in-register via
// cvt_pk_bf16 + permlane32_swap (no P LDS). LDS 64KB.
__global__ __launch_bounds__(256, 2) void attn_k(const u16* __restrict__ Q,
                                                 const u16* __restrict__ K,
                                                 const u16* __restrict__ VT,
                                                 u16* __restrict__ Y) {
  __shared__ __align__(16) u16 lK[2][64 * 128];
  __shared__ __align__(16) u16 lV[2][128 * 64];

  const int t = threadIdx.x;
  const int lane = t & 63;
  const int l31 = lane & 31, hb = lane >> 5;
  const int w = t >> 6;

  const int id = blockIdx.x;
  const int xcd = id & 7, pos = id >> 3;
  const int bh = xcd + ((pos >> 4) << 3);
  const int qt = 15 - (pos & 15);  // heavy q-tiles first
  const int b = bh >> 4, h = bh & 15, kh = h >> 2;

  const size_t qbase = (size_t)(b * 16 + h) * 2048 * 128;
  const size_t kbase = (size_t)(b * 4 + kh) * 2048 * 128;
  const size_t vbase = (size_t)(b * 4 + kh) * 128 * 2048;

  const int q0 = qt * 128;
  const int qrow = q0 + w * 32 + l31;

  // Q fragments: B-operand, q = lane&31, d = j16*16 + hb*8 + e
  short8v qf[8];
#pragma unroll
  for (int j16 = 0; j16 < 8; ++j16)
    qf[j16] = *(const short8v*)(Q + qbase + (size_t)qrow * 128 + j16 * 16 + hb * 8);

  float m_run = -3.0e38f, l_run = 0.f;
  f32x16 oacc[4];
#pragma unroll
  for (int db = 0; db < 4; ++db)
#pragma unroll
    for (int rg = 0; rg < 16; ++rg) oacc[db][rg] = 0.f;

  const int ntile = 2 * qt + 2;

  auto stage = [&](int buf, int j) {
    const int kv0 = j * 64;
#pragma unroll
    for (int i = 0; i < 4; ++i) {
      int off = i * 4096 + t * 16;
      int r = off >> 8;
      int sl = (off >> 4) & 15;
      int gs = sl ^ (r & 7);
      gload16((const char*)K + (kbase + (size_t)(kv0 + r) * 128 + gs * 8) * 2,
              (char*)lK[buf] + i * 4096 + w * 1024);
    }
#pragma unroll
    for (int i = 0; i < 4; ++i) {
      int off = i * 4096 + t * 16;
      int r = off >> 7;
      int sl = (off >> 4) & 7;
      int gs = sl ^ (r & 7);
      gload16((const char*)VT + (vbase + (size_t)r * 2048 + kv0 + gs * 8) * 2,
              (char*)lV[buf] + i * 4096 + w * 1024);
    }
  };

  stage(0, 0);
  __syncthreads();

  for (int jj = 0; jj < ntile; ++jj) {
    const int cur = jj & 1;
    if (jj + 1 < ntile) stage(cur ^ 1, jj + 1);

    const char* lKc = (const char*)lK[cur];
    const char* lVc = (const char*)lV[cur];
    const int kv0 = jj * 64;

    // QK^T: S^T[k][q], k = kv0 + kb*32 + (rg&3)+8*(rg>>2)+4*hb, q = qrow
    f32x16 sacc[2];
#pragma unroll
    for (int kb = 0; kb < 2; ++kb)
#pragma unroll
      for (int rg = 0; rg < 16; ++rg) sacc[kb][rg] = 0.f;

    __builtin_amdgcn_s_setprio(1);
#pragma unroll
    for (int j16 = 0; j16 < 8; ++j16) {
      const int c = j16 * 2 + hb;
#pragma unroll
      for (int kb = 0; kb < 2; ++kb) {
        int kr = kb * 32 + l31;
        short8v kf = *(const short8v*)(lKc + kr * 256 + ((c ^ (kr & 7)) << 4));
        sacc[kb] = __builtin_amdgcn_mfma_f32_32x32x16_bf16(kf, qf[j16],
                                                           sacc[kb], 0, 0, 0);
      }
    }
    __builtin_amdgcn_s_setprio(0);

    // causal mask (last two tiles cover the diagonal 128-block)
    if (jj >= ntile - 2) {
      const int mb = kv0 + 4 * hb - qrow;
#pragma unroll
      for (int kb = 0; kb < 2; ++kb)
#pragma unroll
        for (int rg = 0; rg < 16; ++rg)
          if (mb + kb * 32 + (rg & 3) + 8 * (rg >> 2) > 0)
            sacc[kb][rg] = -1.0e38f;
    }

    // row max: pairwise tree (depth 5) + 1 cross-half shfl
    float mt0[16];
#pragma unroll
    for (int rg = 0; rg < 16; ++rg) mt0[rg] = fmaxf(sacc[0][rg], sacc[1][rg]);
#pragma unroll
    for (int rg = 0; rg < 8; ++rg) mt0[rg] = fmaxf(mt0[rg], mt0[rg + 8]);
#pragma unroll
    for (int rg = 0; rg < 4; ++rg) mt0[rg] = fmaxf(mt0[rg], mt0[rg + 4]);
    float mx = fmaxf(fmaxf(mt0[0], mt0[1]), fmaxf(mt0[2], mt0[3]));
    mx = fmaxf(mx, __shfl_xor(mx, 32, 64));

    // defer-max rescale
    if (__any(mx > m_run + 8.f)) {
      float mn = fmaxf(m_run, mx);
      float corr = exp2f(m_run - mn);
      m_run = mn;
      l_run *= corr;
#pragma unroll
      for (int db = 0; db < 4; ++db)
#pragma unroll
        for (int rg = 0; rg < 16; ++rg) oacc[db][rg] *= corr;
    }

    // p = exp2(s - m); row sum (pairwise); pack P^T fragments in-register
    float sm0[16];
#pragma unroll
    for (int kb = 0; kb < 2; ++kb)
#pragma unroll
      for (int rg = 0; rg < 16; ++rg)
        sacc[kb][rg] = exp2f(sacc[kb][rg] - m_run);
#pragma unroll
    for (int rg = 0; rg < 16; ++rg) sm0[rg] = sacc[0][rg] + sacc[1][rg];
#pragma unroll
    for (int rg = 0; rg < 8; ++rg) sm0[rg] += sm0[rg + 8];
#pragma unroll
    for (int rg = 0; rg < 4; ++rg) sm0[rg] += sm0[rg + 4];
    float sm = (sm0[0] + sm0[1]) + (sm0[2] + sm0[3]);
    sm += __shfl_xor(sm, 32, 64);
    l_run += sm;

    // pack P^T: cvt_pk pairs + permlane32_swap (r7-verified word assembly)
    short8v pa[4];
#pragma unroll
    for (int kb = 0; kb < 2; ++kb) {
      u32 pw00, pw01, pw10, pw11, pw20, pw21, pw30, pw31;
      asm("v_cvt_pk_bf16_f32 %0, %1, %2" : "=v"(pw00) : "v"(sacc[kb][0]), "v"(sacc[kb][1]));
      asm("v_cvt_pk_bf16_f32 %0, %1, %2" : "=v"(pw01) : "v"(sacc[kb][2]), "v"(sacc[kb][3]));
      asm("v_cvt_pk_bf16_f32 %0, %1, %2" : "=v"(pw10) : "v"(sacc[kb][4]), "v"(sacc[kb][5]));
      asm("v_cvt_pk_bf16_f32 %0, %1, %2" : "=v"(pw11) : "v"(sacc[kb][6]), "v"(sacc[kb][7]));
      asm("v_cvt_pk_bf16_f32 %0, %1, %2" : "=v"(pw20) : "v"(sacc[kb][8]), "v"(sacc[kb][9]));
      asm("v_cvt_pk_bf16_f32 %0, %1, %2" : "=v"(pw21) : "v"(sacc[kb][10]), "v"(sacc[kb][11]));
      asm("v_cvt_pk_bf16_f32 %0, %1, %2" : "=v"(pw30) : "v"(sacc[kb][12]), "v"(sacc[kb][13]));
      asm("v_cvt_pk_bf16_f32 %0, %1, %2" : "=v"(pw31) : "v"(sacc[kb][14]), "v"(sacc[kb][15]));
      u32x2 a0 = __builtin_amdgcn_permlane32_swap(pw00, pw10, false, false);
      u32x2 a1 = __builtin_amdgcn_permlane32_swap(pw01, pw11, false, false);
      u32x4 wv0; wv0[0] = a0[0]; wv0[1] = a1[0]; wv0[2] = a0[1]; wv0[3] = a1[1];
      pa[kb * 2 + 0] = __builtin_bit_cast(short8v, wv0);
      u32x2 b0 = __builtin_amdgcn_permlane32_swap(pw20, pw30, false, false);
      u32x2 b1 = __builtin_amdgcn_permlane32_swap(pw21, pw31, false, false);
      u32x4 wv1; wv1[0] = b0[0]; wv1[1] = b1[0]; wv1[2] = b0[1]; wv1[3] = b1[1];
      pa[kb * 2 + 1] = __builtin_bit_cast(short8v, wv1);
    }

    // PV: O^T[d][q] += V^T[d][s] * P^T[s][q]
    __builtin_amdgcn_s_setprio(1);
#pragma unroll
    for (int sc = 0; sc < 4; ++sc) {
      const int c = sc * 2 + hb;
#pragma unroll
      for (int db = 0; db < 4; ++db) {
        int vr = db * 32 + l31;
        short8v vf = *(const short8v*)(lVc + vr * 128 + ((c ^ (vr & 7)) << 4));
        oacc[db] = __builtin_amdgcn_mfma_f32_32x32x16_bf16(vf, pa[sc],
                                                           oacc[db], 0, 0, 0);
      }
    }
    __builtin_amdgcn_s_setprio(0);

    __syncthreads();
  }

  // epilogue: lane-local normalize, pack pairs, store 8B chunks
  const float inv = 1.0f / l_run;
  u16* yp = Y + ((size_t)b * 2048 + qrow) * 2048 + h * 128;
#pragma unroll
  for (int db = 0; db < 4; ++db)
#pragma unroll
    for (int j = 0; j < 4; ++j) {
      float a0 = oacc[db][4 * j] * inv, a1 = oacc[db][4 * j + 1] * inv;
      float a2 = oacc[db][4 * j + 2] * inv, a3 = oacc[db][4 * j + 3] * inv;
      u32 w0, w1;
      asm("v_cvt_pk_bf16_f32 %0, %1, %2" : "=v"(w0) : "v"(a0), "v"(a1));
      asm("v_cvt_pk_bf16_f32 %0, %1, %2" : "=v"(w1) : "v"(a2), "v"(a3));
      *(u32x2*)(yp + db * 32 + 8 * j + 4 * hb) = (u32x2){w0, w1};
    }
}

// ---------------- RMSNorm ----------------
__global__ __launch_bounds__(256) void rmsnorm_k(const u16* __restrict__ Yb,
                                                 const float* __restrict__ nw,
                                                 float* __restrict__ out) {
  const int row = blockIdx.x;
  const int t = threadIdx.x;
  const u16* yr = Yb + (size_t)row * 2048 + t * 8;
  short8v v = *(const short8v*)yr;
  float x[8];
  float ss = 0.f;
#pragma unroll
  for (int j = 0; j < 8; ++j) {
    x[j] = b2f((u16)v[j]);
    ss += x[j] * x[j];
  }
#pragma unroll
  for (int dm = 1; dm < 64; dm <<= 1) ss += __shfl_xor(ss, dm, 64);
  __shared__ float red[4];
  if ((t & 63) == 0) red[t >> 6] = ss;
  __syncthreads();
  float tot = red[0] + red[1] + red[2] + red[3];
  float inv = rsqrtf(tot * (1.0f / 2048.0f) + 1e-6f);
  float* op = out + (size_t)row * 2048 + t * 8;
  const float* wp = nw + t * 8;
  f32x4 o0, o1;
#pragma unroll
  for (int j = 0; j < 4; ++j) o0[j] = x[j] * inv * wp[j];
#pragma unroll
  for (int j = 0; j < 4; ++j) o1[j] = x[4 + j] * inv * wp[4 + j];
  *(f32x4*)op = o0;
  *(f32x4*)(op + 4) = o1;
}

extern "C" void kernel_launch(void* const* d_in, const int* in_sizes, int n_in,
                              void* d_out, int out_size, void* d_ws,
                              size_t ws_size, hipStream_t stream) {
  (void)in_sizes; (void)n_in; (void)out_size; (void)ws_size;
  const float* x = (const float*)d_in[0];
  const float* w_attn = (const float*)d_in[1];
  const float* w_proj = (const float*)d_in[2];
  const float* norm_w = (const float*)d_in[3];
  float* out = (float*)d_out;
  char* ws = (char*)d_ws;

  size_t off = 0;
  auto alloc = [&](size_t n) {
    size_t r = off;
    off += (n + 255) & ~(size_t)255;
    return r;
  };
  u16* xb = (u16*)(ws + alloc(33554432));     // x bf16 [8192][2048]
  u16* wabT = (u16*)(ws + alloc(12582912));   // w_attn^T bf16 [3072][2048]
  u16* qkv = (u16*)(ws + alloc(50331648));    // [8192][3072]
  u16* q_r = (u16*)(ws + alloc(33554432));    // [4][16][2048][128]
  u16* vT = (u16*)(ws + alloc(8388608));      // [4][4][128][2048]
  u16* wpT = (u16*)(ws + alloc(8388608));     // w_proj^T bf16 [2048][2048]
  float* cosT = (float*)(ws + alloc(524288)); // [2048][64]
  float* sinT = (float*)(ws + alloc(524288));
  u16* k_r = wabT;  // reuse (dead after GEMM1)
  u16* y = xb;      // reuse: attn out [8192][2048]
  u16* y2 = qkv;    // reuse: proj out [8192][2048]

  cvt_x_k<<<8192, 256, 0, stream>>>(x, xb);
  transpose_cvt_k<<<dim3(48, 32), 256, 0, stream>>>(w_attn, wabT, 2048, 3072);
  transpose_cvt_k<<<dim3(32, 32), 256, 0, stream>>>(w_proj, wpT, 2048, 2048);
  rope_table_k<<<512, 256, 0, stream>>>(cosT, sinT);
  gemm256_k<<<dim3(12, 32), 512, 0, stream>>>(xb, wabT, qkv, 3072, 2048);
  scatter_vtrans_k<<<9216, 256, 0, stream>>>(qkv, cosT, sinT, q_r, k_r, vT);
  attn_k<<<dim3(1024), 256, 0, stream>>>(q_r, k_r, vT, y);
  gemm256_k<<<dim3(8, 32), 512, 0, stream>>>(y, wpT, y2, 2048, 2048);
  rmsnorm_k<<<8192, 256, 0, stream>>>(y2, norm_w, out);
}

// Round 14
// 403.267 us; speedup vs baseline: 1.5777x; 1.0283x over previous
//
#include <hip/hip_runtime.h>

#define DEVI __device__ __forceinline__

using u16 = unsigned short;
using u32 = unsigned int;

typedef __attribute__((ext_vector_type(8))) short short8v;
typedef __attribute__((ext_vector_type(4))) float f32x4;
typedef __attribute__((ext_vector_type(16))) float f32x16;
typedef __attribute__((ext_vector_type(2))) u32 u32x2;
typedef __attribute__((ext_vector_type(4))) u32 u32x4;

DEVI u16 f2b(float f) {
  u32 u = __builtin_bit_cast(u32, f);
  u += 0x7fffu + ((u >> 16) & 1u);
  return (u16)(u >> 16);
}
DEVI float b2f(u16 b) { return __builtin_bit_cast(float, (u32)b << 16); }

DEVI void gload16(const void* g, void* l) {
  __builtin_amdgcn_global_load_lds(
      (const __attribute__((address_space(1))) void*)g,
      (__attribute__((address_space(3))) void*)l, 16, 0, 0);
}

// ---------------- x: fp32 -> bf16 ----------------
__global__ __launch_bounds__(256) void cvt_x_k(const float* __restrict__ in,
                                               u16* __restrict__ out) {
  size_t i = ((size_t)blockIdx.x * 256 + threadIdx.x) * 8;
  f32x4 a = *(const f32x4*)(in + i);
  f32x4 c = *(const f32x4*)(in + i + 4);
  short8v o;
  o[0] = (short)f2b(a[0]); o[1] = (short)f2b(a[1]);
  o[2] = (short)f2b(a[2]); o[3] = (short)f2b(a[3]);
  o[4] = (short)f2b(c[0]); o[5] = (short)f2b(c[1]);
  o[6] = (short)f2b(c[2]); o[7] = (short)f2b(c[3]);
  *(short8v*)(out + i) = o;
}

// ---------------- transpose + cvt ----------------
__global__ __launch_bounds__(256) void transpose_cvt_k(
    const float* __restrict__ in, u16* __restrict__ out, int R, int Ccols) {
  __shared__ u16 tile[64][65];
  const int r0 = blockIdx.y * 64, c0 = blockIdx.x * 64;
  const int tx = threadIdx.x & 63, ty = threadIdx.x >> 6;
#pragma unroll
  for (int jj = 0; jj < 16; ++jj) {
    int r = ty + jj * 4;
    tile[r][tx] = f2b(in[(size_t)(r0 + r) * Ccols + c0 + tx]);
  }
  __syncthreads();
#pragma unroll
  for (int jj = 0; jj < 16; ++jj) {
    int c = ty + jj * 4;
    out[(size_t)(c0 + c) * R + r0 + tx] = tile[tx][c];
  }
}

// ---------------- rope table ----------------
__global__ __launch_bounds__(256) void rope_table_k(float* __restrict__ cosT,
                                                    float* __restrict__ sinT) {
  int idx = blockIdx.x * 256 + threadIdx.x;
  int s = idx >> 6, i = idx & 63;
  float inv_freq = expf(-(float)i * (1.0f / 64.0f) * 9.210340371976184f);
  float ang = (float)s * inv_freq;
  cosT[idx] = cosf(ang);
  sinT[idx] = sinf(ang);
}

// ---------------- rope + scatter q,k (8B/lane vectorized) ----------------
// Each iteration handles 2 adjacent rope pairs (4 u16); d is a multiple of 4
// so both pairs stay within one head row and the 8B store is aligned.
__global__ __launch_bounds__(256) void rope_scatter_k(
    const u16* __restrict__ qkv, const float* __restrict__ cosT,
    const float* __restrict__ sinT, u16* __restrict__ q_r,
    u16* __restrict__ k_r) {
  const float QS = 0.08838834764831845f * 1.4426950408889634f;
  const int row = blockIdx.x;
  const int b = row >> 11, s = row & 2047;
  const u16* in = qkv + (size_t)row * 3072;
  const float* cp = cosT + s * 64;
  const float* sp = sinT + s * 64;
  for (int p2 = threadIdx.x; p2 < 640; p2 += 256) {
    int f0 = p2 * 4;
    u32x2 pr = *(const u32x2*)(in + f0);
    float xa0 = b2f((u16)(pr[0] & 0xffffu));
    float xa1 = b2f((u16)(pr[0] >> 16));
    float xb0 = b2f((u16)(pr[1] & 0xffffu));
    float xb1 = b2f((u16)(pr[1] >> 16));
    int d, head;
    u16* dst;
    bool isq = (f0 < 2048);
    if (isq) {
      head = f0 >> 7; d = f0 & 127;
      dst = q_r + (((size_t)(b * 16 + head)) * 2048 + s) * 128 + d;
    } else {
      int idx = f0 - 2048;
      head = idx >> 7; d = idx & 127;
      dst = k_r + (((size_t)(b * 4 + head)) * 2048 + s) * 128 + d;
    }
    int i = d >> 1;
    float c0 = cp[i], s0v = sp[i];
    float c1 = cp[i + 1], s1v = sp[i + 1];
    float oa0 = xa0 * c0 - xa1 * s0v;
    float oa1 = xa0 * s0v + xa1 * c0;
    float ob0 = xb0 * c1 - xb1 * s1v;
    float ob1 = xb0 * s1v + xb1 * c1;
    if (isq) { oa0 *= QS; oa1 *= QS; ob0 *= QS; ob1 *= QS; }
    u32x2 o;
    o[0] = (u32)f2b(oa0) | ((u32)f2b(oa1) << 16);
    o[1] = (u32)f2b(ob0) | ((u32)f2b(ob1) << 16);
    *(u32x2*)dst = o;
  }
}

// ---------------- v transpose ----------------
__global__ __launch_bounds__(256) void v_trans_k(const u16* __restrict__ qkv,
                                                 u16* __restrict__ vT) {
  __shared__ u16 tile[64][65];
  const int s0 = blockIdx.x * 64, d0 = blockIdx.y * 64;
  const int bk = blockIdx.z;
  const int b = bk >> 2, kh = bk & 3;
  const int tx = threadIdx.x & 63, ty = threadIdx.x >> 6;
  const u16* src = qkv + ((size_t)b * 2048) * 3072 + 2560 + kh * 128;
#pragma unroll
  for (int jj = 0; jj < 16; ++jj) {
    int s = ty + jj * 4;
    tile[s][tx] = src[(size_t)(s0 + s) * 3072 + d0 + tx];
  }
  __syncthreads();
  u16* dst = vT + (((size_t)bk * 128 + d0) * 2048) + s0;
#pragma unroll
  for (int jj = 0; jj < 16; ++jj) {
    int dd = ty + jj * 4;
    dst[(size_t)dd * 2048 + tx] = tile[tx][dd];
  }
}

// ---------------- 256x256 8-phase GEMM ----------------
DEVI short8v ldf(const char* half, int r, int slot) {
  return *(const short8v*)(half + r * 64 + (((slot) ^ (r & 3)) << 4));
}

DEVI void stg(const u16* __restrict__ G, int row0, int Kd, int T, int kh,
              char* dst, int t, int w) {
#pragma unroll
  for (int i = 0; i < 2; ++i) {
    int off = i * 8192 + t * 16;
    int r = off >> 6;
    int gs = ((off >> 4) & 3) ^ (r & 3);
    gload16((const char*)G +
                (((size_t)(row0 + r) * Kd) + T * 64 + kh * 32 + gs * 8) * 2,
            dst + i * 8192 + w * 1024);
  }
}

#define VM4 asm volatile("s_waitcnt vmcnt(4)" ::: "memory")
#define PH(P2, KS, CH, STAGE_STMT, TAILWAIT)                                   \
  {                                                                            \
    if ((CH) == 0) {                                                           \
      _Pragma("unroll") for (int mt = 0; mt < 8; ++mt) af[mt] =                \
          ldf(Ab + (P2) * 32768 + (KS) * 16384, wm * 128 + mt * 16 + lo, hi);  \
    }                                                                          \
    bf0 = ldf(Bb + (P2) * 32768 + (KS) * 16384, wn * 64 + (CH) * 32 + lo, hi);\
    bf1 = ldf(Bb + (P2) * 32768 + (KS) * 16384,                                \
              wn * 64 + (CH) * 32 + 16 + lo, hi);                              \
    STAGE_STMT;                                                                \
    __builtin_amdgcn_sched_barrier(0);                                         \
    __builtin_amdgcn_s_barrier();                                              \
    asm volatile("s_waitcnt lgkmcnt(0)" ::: "memory");                         \
    __builtin_amdgcn_sched_barrier(0);                                         \
    __builtin_amdgcn_s_setprio(1);                                             \
    _Pragma("unroll") for (int mt = 0; mt < 8; ++mt) {                         \
      acc[mt][(CH) * 2] = __builtin_amdgcn_mfma_f32_16x16x32_bf16(             \
          af[mt], bf0, acc[mt][(CH) * 2], 0, 0, 0);                            \
      acc[mt][(CH) * 2 + 1] = __builtin_amdgcn_mfma_f32_16x16x32_bf16(         \
          af[mt], bf1, acc[mt][(CH) * 2 + 1], 0, 0, 0);                        \
    }                                                                          \
    __builtin_amdgcn_s_setprio(0);                                             \
    TAILWAIT;                                                                  \
    __builtin_amdgcn_sched_barrier(0);                                         \
    __builtin_amdgcn_s_barrier();                                              \
    __builtin_amdgcn_sched_barrier(0);                                         \
  }

__global__ __launch_bounds__(512, 2) void gemm256_k(const u16* __restrict__ A,
                                                    const u16* __restrict__ BT,
                                                    u16* __restrict__ C, int N,
                                                    int Kd) {
  __shared__ __align__(16) char lds[131072];
  char* Ab = lds;
  char* Bb = lds + 65536;

  const int t = threadIdx.x;
  const int lane = t & 63, lo = lane & 15, hi = lane >> 4;
  const int w = t >> 6, wm = w >> 2, wn = w & 3;

  const int ntx = gridDim.x;
  const int nwg = ntx * gridDim.y;
  const int orig = blockIdx.y * ntx + blockIdx.x;
  const int cpx = nwg >> 3;
  const int swz = (orig & 7) * cpx + (orig >> 3);
  const int m0 = (swz / ntx) * 256, n0 = (swz % ntx) * 256;

  f32x4 acc[8][4];
#pragma unroll
  for (int a = 0; a < 8; ++a)
#pragma unroll
    for (int c = 0; c < 4; ++c) acc[a][c] = (f32x4){0.f, 0.f, 0.f, 0.f};

  short8v af[8], bf0, bf1;

  const int NK = Kd >> 6;
  const int NK2 = NK >> 1;

  stg(A, m0, Kd, 0, 0, Ab + 0, t, w);
  stg(BT, n0, Kd, 0, 0, Bb + 0, t, w);
  stg(A, m0, Kd, 0, 1, Ab + 16384, t, w);
  stg(BT, n0, Kd, 0, 1, Bb + 16384, t, w);
  stg(A, m0, Kd, 1, 0, Ab + 32768, t, w);
  stg(BT, n0, Kd, 1, 0, Bb + 32768, t, w);
  VM4;
  __builtin_amdgcn_sched_barrier(0);
  __builtin_amdgcn_s_barrier();
  __builtin_amdgcn_sched_barrier(0);

  for (int kt2 = 0; kt2 < NK2; ++kt2) {
    int T1v = 2 * kt2 + 1;
    int T2v = 2 * kt2 + 2; if (T2v > NK - 1) T2v = NK - 1;
    int T3v = 2 * kt2 + 3; if (T3v > NK - 1) T3v = NK - 1;
    PH(0, 0, 0, stg(A, m0, Kd, T1v, 1, Ab + 49152, t, w), (void)0);
    PH(0, 0, 1, stg(BT, n0, Kd, T1v, 1, Bb + 49152, t, w), (void)0);
    PH(0, 1, 0, stg(A, m0, Kd, T2v, 0, Ab + 0, t, w), (void)0);
    PH(0, 1, 1, stg(BT, n0, Kd, T2v, 0, Bb + 0, t, w), VM4);
    PH(1, 0, 0, stg(A, m0, Kd, T2v, 1, Ab + 16384, t, w), (void)0);
    PH(1, 0, 1, stg(BT, n0, Kd, T2v, 1, Bb + 16384, t, w), (void)0);
    PH(1, 1, 0, stg(A, m0, Kd, T3v, 0, Ab + 32768, t, w), (void)0);
    PH(1, 1, 1, stg(BT, n0, Kd, T3v, 0, Bb + 32768, t, w), VM4);
  }
  asm volatile("s_waitcnt vmcnt(0)" ::: "memory");

#pragma unroll
  for (int mt = 0; mt < 8; ++mt)
#pragma unroll
    for (int nt = 0; nt < 4; ++nt)
#pragma unroll
      for (int r = 0; r < 4; ++r) {
        int row = m0 + wm * 128 + mt * 16 + hi * 4 + r;
        int col = n0 + wn * 64 + nt * 16 + lo;
        C[(size_t)row * N + col] = f2b(acc[mt][nt][r]);
      }
}

// ---------------- flash attention: 32x32 MFMA, in-register P (r7 base) ------
// K-swizzle upgraded to &15 involution (16 slots, 2 lanes/slot-group ->
// conflict-free QK ds_read_b128). V stays &7 (8-slot rows, XOR-limit).
__global__ __launch_bounds__(256, 2) void attn_k(const u16* __restrict__ Q,
                                                 const u16* __restrict__ K,
                                                 const u16* __restrict__ VT,
                                                 u16* __restrict__ Y) {
  __shared__ __align__(16) u16 lK[2][64 * 128];
  __shared__ __align__(16) u16 lV[2][128 * 64];

  const int t = threadIdx.x;
  const int lane = t & 63;
  const int l31 = lane & 31, hb = lane >> 5;
  const int w = t >> 6;

  const int id = blockIdx.x;
  const int xcd = id & 7, pos = id >> 3;
  const int bh = xcd + ((pos >> 4) << 3);
  const int qt = 15 - (pos & 15);  // heavy q-tiles first
  const int b = bh >> 4, h = bh & 15, kh = h >> 2;

  const size_t qbase = (size_t)(b * 16 + h) * 2048 * 128;
  const size_t kbase = (size_t)(b * 4 + kh) * 2048 * 128;
  const size_t vbase = (size_t)(b * 4 + kh) * 128 * 2048;

  const int q0 = qt * 128;
  const int qrow = q0 + w * 32 + l31;

  // Q fragments: B-operand, q = lane&31, d = j16*16 + hb*8 + e
  short8v qf[8];
#pragma unroll
  for (int j16 = 0; j16 < 8; ++j16)
    qf[j16] = *(const short8v*)(Q + qbase + (size_t)qrow * 128 + j16 * 16 + hb * 8);

  float m_run = -3.0e38f, l_run = 0.f;
  f32x16 oacc[4];
#pragma unroll
  for (int db = 0; db < 4; ++db)
#pragma unroll
    for (int rg = 0; rg < 16; ++rg) oacc[db][rg] = 0.f;

  const int ntile = 2 * qt + 2;

  auto stage = [&](int buf, int j) {
    const int kv0 = j * 64;
#pragma unroll
    for (int i = 0; i < 4; ++i) {
      int off = i * 4096 + t * 16;
      int r = off >> 8;
      int sl = (off >> 4) & 15;
      int gs = sl ^ (r & 15);  // 16-slot involution (conflict-free reads)
      gload16((const char*)K + (kbase + (size_t)(kv0 + r) * 128 + gs * 8) * 2,
              (char*)lK[buf] + i * 4096 + w * 1024);
    }
#pragma unroll
    for (int i = 0; i < 4; ++i) {
      int off = i * 4096 + t * 16;
      int r = off >> 7;
      int sl = (off >> 4) & 7;
      int gs = sl ^ (r & 7);
      gload16((const char*)VT + (vbase + (size_t)r * 2048 + kv0 + gs * 8) * 2,
              (char*)lV[buf] + i * 4096 + w * 1024);
    }
  };

  stage(0, 0);
  __syncthreads();

  for (int jj = 0; jj < ntile; ++jj) {
    const int cur = jj & 1;
    if (jj + 1 < ntile) stage(cur ^ 1, jj + 1);

    const char* lKc = (const char*)lK[cur];
    const char* lVc = (const char*)lV[cur];
    const int kv0 = jj * 64;

    // QK^T: S^T[k][q], k = kv0 + kb*32 + (rg&3)+8*(rg>>2)+4*hb, q = qrow
    f32x16 sacc[2];
#pragma unroll
    for (int kb = 0; kb < 2; ++kb)
#pragma unroll
      for (int rg = 0; rg < 16; ++rg) sacc[kb][rg] = 0.f;

    __builtin_amdgcn_s_setprio(1);
#pragma unroll
    for (int j16 = 0; j16 < 8; ++j16) {
      const int c = j16 * 2 + hb;
#pragma unroll
      for (int kb = 0; kb < 2; ++kb) {
        int kr = kb * 32 + l31;
        short8v kf = *(const short8v*)(lKc + kr * 256 + ((c ^ (kr & 15)) << 4));
        sacc[kb] = __builtin_amdgcn_mfma_f32_32x32x16_bf16(kf, qf[j16],
                                                           sacc[kb], 0, 0, 0);
      }
    }
    __builtin_amdgcn_s_setprio(0);

    // causal mask (last two tiles cover the diagonal 128-block)
    if (jj >= ntile - 2) {
      const int mb = kv0 + 4 * hb - qrow;
#pragma unroll
      for (int kb = 0; kb < 2; ++kb)
#pragma unroll
        for (int rg = 0; rg < 16; ++rg)
          if (mb + kb * 32 + (rg & 3) + 8 * (rg >> 2) > 0)
            sacc[kb][rg] = -1.0e38f;
    }

    // row max: pairwise tree (depth 5) + 1 cross-half shfl
    float mt0[16];
#pragma unroll
    for (int rg = 0; rg < 16; ++rg) mt0[rg] = fmaxf(sacc[0][rg], sacc[1][rg]);
#pragma unroll
    for (int rg = 0; rg < 8; ++rg) mt0[rg] = fmaxf(mt0[rg], mt0[rg + 8]);
#pragma unroll
    for (int rg = 0; rg < 4; ++rg) mt0[rg] = fmaxf(mt0[rg], mt0[rg + 4]);
    float mx = fmaxf(fmaxf(mt0[0], mt0[1]), fmaxf(mt0[2], mt0[3]));
    mx = fmaxf(mx, __shfl_xor(mx, 32, 64));

    // defer-max rescale
    if (__any(mx > m_run + 8.f)) {
      float mn = fmaxf(m_run, mx);
      float corr = exp2f(m_run - mn);
      m_run = mn;
      l_run *= corr;
#pragma unroll
      for (int db = 0; db < 4; ++db)
#pragma unroll
        for (int rg = 0; rg < 16; ++rg) oacc[db][rg] *= corr;
    }

    // p = exp2(s - m); row sum (pairwise); pack P^T fragments in-register
    float sm0[16];
#pragma unroll
    for (int kb = 0; kb < 2; ++kb)
#pragma unroll
      for (int rg = 0; rg < 16; ++rg)
        sacc[kb][rg] = exp2f(sacc[kb][rg] - m_run);
#pragma unroll
    for (int rg = 0; rg < 16; ++rg) sm0[rg] = sacc[0][rg] + sacc[1][rg];
#pragma unroll
    for (int rg = 0; rg < 8; ++rg) sm0[rg] += sm0[rg + 8];
#pragma unroll
    for (int rg = 0; rg < 4; ++rg) sm0[rg] += sm0[rg + 4];
    float sm = (sm0[0] + sm0[1]) + (sm0[2] + sm0[3]);
    sm += __shfl_xor(sm, 32, 64);
    l_run += sm;

    // pack P^T: cvt_pk pairs + permlane32_swap (r7-verified word assembly)
    short8v pa[4];
#pragma unroll
    for (int kb = 0; kb < 2; ++kb) {
      u32 pw00, pw01, pw10, pw11, pw20, pw21, pw30, pw31;
      asm("v_cvt_pk_bf16_f32 %0, %1, %2" : "=v"(pw00) : "v"(sacc[kb][0]), "v"(sacc[kb][1]));
      asm("v_cvt_pk_bf16_f32 %0, %1, %2" : "=v"(pw01) : "v"(sacc[kb][2]), "v"(sacc[kb][3]));
      asm("v_cvt_pk_bf16_f32 %0, %1, %2" : "=v"(pw10) : "v"(sacc[kb][4]), "v"(sacc[kb][5]));
      asm("v_cvt_pk_bf16_f32 %0, %1, %2" : "=v"(pw11) : "v"(sacc[kb][6]), "v"(sacc[kb][7]));
      asm("v_cvt_pk_bf16_f32 %0, %1, %2" : "=v"(pw20) : "v"(sacc[kb][8]), "v"(sacc[kb][9]));
      asm("v_cvt_pk_bf16_f32 %0, %1, %2" : "=v"(pw21) : "v"(sacc[kb][10]), "v"(sacc[kb][11]));
      asm("v_cvt_pk_bf16_f32 %0, %1, %2" : "=v"(pw30) : "v"(sacc[kb][12]), "v"(sacc[kb][13]));
      asm("v_cvt_pk_bf16_f32 %0, %1, %2" : "=v"(pw31) : "v"(sacc[kb][14]), "v"(sacc[kb][15]));
      u32x2 a0 = __builtin_amdgcn_permlane32_swap(pw00, pw10, false, false);
      u32x2 a1 = __builtin_amdgcn_permlane32_swap(pw01, pw11, false, false);
      u32x4 wv0; wv0[0] = a0[0]; wv0[1] = a1[0]; wv0[2] = a0[1]; wv0[3] = a1[1];
      pa[kb * 2 + 0] = __builtin_bit_cast(short8v, wv0);
      u32x2 b0 = __builtin_amdgcn_permlane32_swap(pw20, pw30, false, false);
      u32x2 b1 = __builtin_amdgcn_permlane32_swap(pw21, pw31, false, false);
      u32x4 wv1; wv1[0] = b0[0]; wv1[1] = b1[0]; wv1[2] = b0[1]; wv1[3] = b1[1];
      pa[kb * 2 + 1] = __builtin_bit_cast(short8v, wv1);
    }

    // PV: O^T[d][q] += V^T[d][s] * P^T[s][q]
    __builtin_amdgcn_s_setprio(1);
#pragma unroll
    for (int sc = 0; sc < 4; ++sc) {
      const int c = sc * 2 + hb;
#pragma unroll
      for (int db = 0; db < 4; ++db) {
        int vr = db * 32 + l31;
        short8v vf = *(const short8v*)(lVc + vr * 128 + ((c ^ (vr & 7)) << 4));
        oacc[db] = __builtin_amdgcn_mfma_f32_32x32x16_bf16(vf, pa[sc],
                                                           oacc[db], 0, 0, 0);
      }
    }
    __builtin_amdgcn_s_setprio(0);

    __syncthreads();
  }

  // epilogue: lane-local normalize, pack pairs, store 8B chunks
  const float inv = 1.0f / l_run;
  u16* yp = Y + ((size_t)b * 2048 + qrow) * 2048 + h * 128;
#pragma unroll
  for (int db = 0; db < 4; ++db)
#pragma unroll
    for (int j = 0; j < 4; ++j) {
      float a0 = oacc[db][4 * j] * inv, a1 = oacc[db][4 * j + 1] * inv;
      float a2 = oacc[db][4 * j + 2] * inv, a3 = oacc[db][4 * j + 3] * inv;
      u32 w0, w1;
      asm("v_cvt_pk_bf16_f32 %0, %1, %2" : "=v"(w0) : "v"(a0), "v"(a1));
      asm("v_cvt_pk_bf16_f32 %0, %1, %2" : "=v"(w1) : "v"(a2), "v"(a3));
      *(u32x2*)(yp + db * 32 + 8 * j + 4 * hb) = (u32x2){w0, w1};
    }
}

// ---------------- RMSNorm ----------------
__global__ __launch_bounds__(256) void rmsnorm_k(const u16* __restrict__ Yb,
                                                 const float* __restrict__ nw,
                                                 float* __restrict__ out) {
  const int row = blockIdx.x;
  const int t = threadIdx.x;
  const u16* yr = Yb + (size_t)row * 2048 + t * 8;
  short8v v = *(const short8v*)yr;
  float x[8];
  float ss = 0.f;
#pragma unroll
  for (int j = 0; j < 8; ++j) {
    x[j] = b2f((u16)v[j]);
    ss += x[j] * x[j];
  }
#pragma unroll
  for (int dm = 1; dm < 64; dm <<= 1) ss += __shfl_xor(ss, dm, 64);
  __shared__ float red[4];
  if ((t & 63) == 0) red[t >> 6] = ss;
  __syncthreads();
  float tot = red[0] + red[1] + red[2] + red[3];
  float inv = rsqrtf(tot * (1.0f / 2048.0f) + 1e-6f);
  float* op = out + (size_t)row * 2048 + t * 8;
  const float* wp = nw + t * 8;
  f32x4 o0, o1;
#pragma unroll
  for (int j = 0; j < 4; ++j) o0[j] = x[j] * inv * wp[j];
#pragma unroll
  for (int j = 0; j < 4; ++j) o1[j] = x[4 + j] * inv * wp[4 + j];
  *(f32x4*)op = o0;
  *(f32x4*)(op + 4) = o1;
}

extern "C" void kernel_launch(void* const* d_in, const int* in_sizes, int n_in,
                              void* d_out, int out_size, void* d_ws,
                              size_t ws_size, hipStream_t stream) {
  (void)in_sizes; (void)n_in; (void)out_size; (void)ws_size;
  const float* x = (const float*)d_in[0];
  const float* w_attn = (const float*)d_in[1];
  const float* w_proj = (const float*)d_in[2];
  const float* norm_w = (const float*)d_in[3];
  float* out = (float*)d_out;
  char* ws = (char*)d_ws;

  size_t off = 0;
  auto alloc = [&](size_t n) {
    size_t r = off;
    off += (n + 255) & ~(size_t)255;
    return r;
  };
  u16* xb = (u16*)(ws + alloc(33554432));     // x bf16 [8192][2048]
  u16* wabT = (u16*)(ws + alloc(12582912));   // w_attn^T bf16 [3072][2048]
  u16* qkv = (u16*)(ws + alloc(50331648));    // [8192][3072]
  u16* q_r = (u16*)(ws + alloc(33554432));    // [4][16][2048][128]
  u16* vT = (u16*)(ws + alloc(8388608));      // [4][4][128][2048]
  u16* wpT = (u16*)(ws + alloc(8388608));     // w_proj^T bf16 [2048][2048]
  float* cosT = (float*)(ws + alloc(524288)); // [2048][64]
  float* sinT = (float*)(ws + alloc(524288));
  u16* k_r = wabT;  // reuse (dead after GEMM1)
  u16* y = xb;      // reuse: attn out [8192][2048]
  u16* y2 = qkv;    // reuse: proj out [8192][2048]

  cvt_x_k<<<8192, 256, 0, stream>>>(x, xb);
  transpose_cvt_k<<<dim3(48, 32), 256, 0, stream>>>(w_attn, wabT, 2048, 3072);
  transpose_cvt_k<<<dim3(32, 32), 256, 0, stream>>>(w_proj, wpT, 2048, 2048);
  rope_table_k<<<512, 256, 0, stream>>>(cosT, sinT);
  gemm256_k<<<dim3(12, 32), 512, 0, stream>>>(xb, wabT, qkv, 3072, 2048);
  rope_scatter_k<<<8192, 256, 0, stream>>>(qkv, cosT, sinT, q_r, k_r);
  v_trans_k<<<dim3(32, 2, 16), 256, 0, stream>>>(qkv, vT);
  attn_k<<<dim3(1024), 256, 0, stream>>>(q_r, k_r, vT, y);
  gemm256_k<<<dim3(8, 32), 512, 0, stream>>>(y, wpT, y2, 2048, 2048);
  rmsnorm_k<<<8192, 256, 0, stream>>>(y2, norm_w, out);
}